// Round 3
// baseline (934.234 us; speedup 1.0000x reference)
//
#include <hip/hip_runtime.h>
#include <hip/hip_fp16.h>

#define B_   2
#define S_   4096
#define H_   16
#define DK_  128
#define DV_  128
#define CK_  64
#define NC_  (S_/CK_)            // 64 chunks per sequence
#define QSCALE 0.08838834764831845f   // 128^-0.5

#define DOT4(a,b) ((a).x*(b).x + (a).y*(b).y + (a).z*(b).z + (a).w*(b).w)

// 16B-granule XOR swizzles: kill 8-way bank conflicts on multi-row reads.
// SWH: arrays of 16-bit elems (granule = 8 elems). SWV: f32 arrays (granule = 4 elems).
#define SWH(c, r) (((((c) >> 3) ^ (((r) >> 2) & 7)) << 3) | ((c) & 7))
#define SWV(c, r) (((((c) >> 2) ^ (((r) >> 2) & 7)) << 2) | ((c) & 3))

static __device__ __forceinline__ unsigned short f2bf(float x) {
    unsigned u = __float_as_uint(x);
    unsigned r = u + 0x7fffu + ((u >> 16) & 1u);
    return (unsigned short)(r >> 16);
}
static __device__ __forceinline__ float bf2f(unsigned short h) {
    return __uint_as_float(((unsigned)h) << 16);
}
static __device__ __forceinline__ float4 h4tof4(const __half* p) {
    float2 f01 = __half22float2(*(const __half2*)p);
    float2 f23 = __half22float2(*(const __half2*)(p + 2));
    return make_float4(f01.x, f01.y, f23.x, f23.y);
}
static __device__ __forceinline__ void f4toh4(__half* p, float4 v) {
    *(__half2*)p       = __floats2half2_rn(v.x, v.y);
    *(__half2*)(p + 2) = __floats2half2_rn(v.z, v.w);
}

struct f8 { float4 lo, hi; };
// 8 bf16 (uint4) -> 8 f32: 2 VALU ops per uint (shl / and)
static __device__ __forceinline__ f8 unp_bf16x8(uint4 u) {
    f8 r;
    r.lo.x = __uint_as_float(u.x << 16); r.lo.y = __uint_as_float(u.x & 0xffff0000u);
    r.lo.z = __uint_as_float(u.y << 16); r.lo.w = __uint_as_float(u.y & 0xffff0000u);
    r.hi.x = __uint_as_float(u.z << 16); r.hi.y = __uint_as_float(u.z & 0xffff0000u);
    r.hi.z = __uint_as_float(u.w << 16); r.hi.w = __uint_as_float(u.w & 0xffff0000u);
    return r;
}
static __device__ __forceinline__ f8 unp_f16x8(uint4 u) {
    f8 r;
    float2 a = __half22float2(*(__half2*)&u.x), b = __half22float2(*(__half2*)&u.y);
    float2 c = __half22float2(*(__half2*)&u.z), d = __half22float2(*(__half2*)&u.w);
    r.lo = make_float4(a.x, a.y, b.x, b.y);
    r.hi = make_float4(c.x, c.y, d.x, d.y);
    return r;
}

// ---------------- Phase 1: per-chunk (parallel over 2048 chunks) ----------------
// (unchanged)
__global__ __launch_bounds__(256) void dr_phase1(
    const float* __restrict__ Q, const float* __restrict__ K,
    const float* __restrict__ V, const float* __restrict__ G,
    const float* __restrict__ Bt,
    unsigned short* __restrict__ Uw, unsigned short* __restrict__ KCDw,
    unsigned short* __restrict__ ATTNw,
    float* __restrict__ RQw, float* __restrict__ RKw, float* __restrict__ EGw)
{
    __shared__ float kn[64][132];                 // raw k, swizzled
    __shared__ __align__(16) __half bufh[64][136]; // v*beta, then raw q (f16)
    __shared__ float T[64][68];
    __shared__ float tmp[32][36];                 // blocked-inverse scratch
    __shared__ float bet[64], rn[64], epos[64], eneg[64], cL[64], cR[64];

    const int tid = threadIdx.x;
    const int cid = blockIdx.x;
    const int n   = cid & (NC_ - 1);
    const int bh  = cid >> 6;
    const int h   = bh & (H_ - 1);
    const int b   = bh >> 4;
    const int rowbase = (b*S_ + n*CK_)*H_ + h;

    // A: stage raw K (swizzled); wave0: shfl-scan of g, exps, beta
    #pragma unroll
    for (int i = 0; i < 8; ++i) {
        int idx4 = tid + 256*i;
        int r = idx4 >> 5, c0 = (idx4 & 31) << 2;
        *(float4*)&kn[r][c0 ^ (r & 28)] =
            *(const float4*)(K + (size_t)(rowbase + r*H_)*DK_ + c0);
    }
    if (tid < 64) {
        float g = G[rowbase + tid*H_];
        #pragma unroll
        for (int off = 1; off < 64; off <<= 1) {
            float o = __shfl_up(g, off, 64);
            if (tid >= off) g += o;
        }
        float ep = expf(g);
        epos[tid] = ep;
        eneg[tid] = expf(-g);
        bet[tid]  = Bt[rowbase + tid*H_];
        if (tid == 63) EGw[cid] = ep;
    }
    __syncthreads();

    // B: stage v*beta -> f16; k row norms -> rn, cL, cR, RK
    #pragma unroll
    for (int i = 0; i < 8; ++i) {
        int idx4 = tid + 256*i;
        int r = idx4 >> 5, c0 = (idx4 & 31) << 2;
        float bb = bet[r];
        float4 vv = *(const float4*)(V + (size_t)(rowbase + r*H_)*DV_ + c0);
        vv.x *= bb; vv.y *= bb; vv.z *= bb; vv.w *= bb;
        f4toh4(&bufh[r][c0], vv);
    }
    if (tid < 64) {
        const int xr = tid & 28;
        float s = 0.f;
        #pragma unroll
        for (int c = 0; c < 128; c += 4) { float4 x = *(float4*)&kn[tid][c ^ xr]; s += DOT4(x,x); }
        float r_ = rsqrtf(s + 1e-6f);
        rn[tid] = r_;
        RKw[cid*64 + tid] = r_*epos[63]*eneg[tid];
        cL[tid] = bet[tid]*epos[tid]*r_;
        cR[tid] = eneg[tid]*r_;
    }
    __syncthreads();

    // C: T = -strict_lower( cL(i)*cR(j) * (kraw_i . kraw_j) )
    {
        const int i0 = (tid >> 4) << 2, j0 = (tid & 15) << 2;
        const int xi = i0 & 28, xj = j0 & 28;
        float acc[4][4] = {};
        if (j0 <= i0) {
            for (int c = 0; c < 128; c += 4) {
                float4 a0 = *(float4*)&kn[i0  ][c ^ xi], a1 = *(float4*)&kn[i0+1][c ^ xi];
                float4 a2 = *(float4*)&kn[i0+2][c ^ xi], a3 = *(float4*)&kn[i0+3][c ^ xi];
                float4 b0 = *(float4*)&kn[j0  ][c ^ xj], b1 = *(float4*)&kn[j0+1][c ^ xj];
                float4 b2 = *(float4*)&kn[j0+2][c ^ xj], b3 = *(float4*)&kn[j0+3][c ^ xj];
                acc[0][0]+=DOT4(a0,b0); acc[0][1]+=DOT4(a0,b1); acc[0][2]+=DOT4(a0,b2); acc[0][3]+=DOT4(a0,b3);
                acc[1][0]+=DOT4(a1,b0); acc[1][1]+=DOT4(a1,b1); acc[1][2]+=DOT4(a1,b2); acc[1][3]+=DOT4(a1,b3);
                acc[2][0]+=DOT4(a2,b0); acc[2][1]+=DOT4(a2,b1); acc[2][2]+=DOT4(a2,b2); acc[2][3]+=DOT4(a2,b3);
                acc[3][0]+=DOT4(a3,b0); acc[3][1]+=DOT4(a3,b1); acc[3][2]+=DOT4(a3,b2); acc[3][3]+=DOT4(a3,b3);
            }
        }
        #pragma unroll
        for (int x = 0; x < 4; ++x) {
            float fi = cL[i0+x];
            #pragma unroll
            for (int y = 0; y < 4; ++y) {
                int i = i0+x, j = j0+y;
                T[i][j] = (i > j) ? (-fi*cR[j]*acc[x][y]) : 0.f;
            }
        }
    }
    __syncthreads();

    // D1: copy diagonal 16x16 blocks (original -A) into tmp
    {
        float* tf = &tmp[0][0];
        for (int t = tid; t < 1024; t += 256) {
            int d = t >> 8, i = (t >> 4) & 15, j = t & 15;
            tf[t] = T[(d<<4) + i][(d<<4) + j];
        }
    }
    __syncthreads();
    // D2: invert each diagonal block in place, one thread per (block, column)
    if (tid < 64) {
        const float* Ad = &tmp[0][0] + ((tid >> 4) << 8);
        const int j = tid & 15, R = (tid >> 4) << 4;
        for (int i = j+1; i < 16; ++i) {
            float x = Ad[(i<<4) + j];
            for (int l = j+1; l < i; ++l) x += Ad[(i<<4) + l] * T[R+l][R+j];
            T[R+i][R+j] = x;
        }
    }
    __syncthreads();
    // D3: 16 -> 32 (two pairs). X21 = (I+X22) * T21 * (I+X11)
    {
        const int p = tid >> 7, rem = tid & 127, i = rem >> 3, j0 = (rem & 7) << 1;
        const int bb2 = p << 5;
        float x0 = T[bb2+16+i][bb2+j0], x1 = T[bb2+16+i][bb2+j0+1];
        for (int l = j0+1; l < 16; ++l) {
            float a = T[bb2+16+i][bb2+l];
            x0 += a * T[bb2+l][bb2+j0];
            if (l > j0+1) x1 += a * T[bb2+l][bb2+j0+1];
        }
        tmp[(p<<4)+i][j0] = x0; tmp[(p<<4)+i][j0+1] = x1;
        __syncthreads();
        float y0 = tmp[(p<<4)+i][j0], y1 = tmp[(p<<4)+i][j0+1];
        for (int l = 0; l < i; ++l) {
            float a = T[bb2+16+i][bb2+16+l];
            y0 += a * tmp[(p<<4)+l][j0];
            y1 += a * tmp[(p<<4)+l][j0+1];
        }
        T[bb2+16+i][bb2+j0] = y0; T[bb2+16+i][bb2+j0+1] = y1;
    }
    __syncthreads();
    // D4: 32 -> 64
    {
        const int i = tid >> 3, j0 = (tid & 7) << 2;
        float x0 = T[32+i][j0], x1 = T[32+i][j0+1], x2 = T[32+i][j0+2], x3 = T[32+i][j0+3];
        for (int l = j0+1; l < 32; ++l) {
            float a = T[32+i][l];
            x0 += a * T[l][j0];
            if (l > j0+1) x1 += a * T[l][j0+1];
            if (l > j0+2) x2 += a * T[l][j0+2];
            if (l > j0+3) x3 += a * T[l][j0+3];
        }
        tmp[i][j0] = x0; tmp[i][j0+1] = x1; tmp[i][j0+2] = x2; tmp[i][j0+3] = x3;
        __syncthreads();
        float y0 = tmp[i][j0], y1 = tmp[i][j0+1], y2 = tmp[i][j0+2], y3 = tmp[i][j0+3];
        for (int l = 0; l < i; ++l) {
            float a = T[32+i][32+l];
            y0 += a * tmp[l][j0];   y1 += a * tmp[l][j0+1];
            y2 += a * tmp[l][j0+2]; y3 += a * tmp[l][j0+3];
        }
        T[32+i][j0] = y0; T[32+i][j0+1] = y1; T[32+i][j0+2] = y2; T[32+i][j0+3] = y3;
    }
    __syncthreads();

    // E: U = (I+T) @ (v*beta),  KCD = (I+T) @ (k*beta*exp(gcs))  -> bf16
    {
        unsigned short* Up = Uw + (size_t)cid*(CK_*DV_);
        for (int tt = tid; tt < 512; tt += 256) {
            const int i0 = (tt >> 5) << 2, c0 = (tt & 31) << 2;
            float4 acc[4];
            #pragma unroll
            for (int x = 0; x < 4; ++x) acc[x] = h4tof4(&bufh[i0+x][c0]);
            for (int j0 = 0; j0 <= i0; j0 += 4) {
                float4 t0 = *(float4*)&T[i0][j0],   t1 = *(float4*)&T[i0+1][j0];
                float4 t2 = *(float4*)&T[i0+2][j0], t3 = *(float4*)&T[i0+3][j0];
                float4 b0 = h4tof4(&bufh[j0][c0]),   b1 = h4tof4(&bufh[j0+1][c0]);
                float4 b2 = h4tof4(&bufh[j0+2][c0]), b3 = h4tof4(&bufh[j0+3][c0]);
                acc[0].x += t0.x*b0.x + t0.y*b1.x + t0.z*b2.x + t0.w*b3.x;
                acc[0].y += t0.x*b0.y + t0.y*b1.y + t0.z*b2.y + t0.w*b3.y;
                acc[0].z += t0.x*b0.z + t0.y*b1.z + t0.z*b2.z + t0.w*b3.z;
                acc[0].w += t0.x*b0.w + t0.y*b1.w + t0.z*b2.w + t0.w*b3.w;
                acc[1].x += t1.x*b0.x + t1.y*b1.x + t1.z*b2.x + t1.w*b3.x;
                acc[1].y += t1.x*b0.y + t1.y*b1.y + t1.z*b2.y + t1.w*b3.y;
                acc[1].z += t1.x*b0.z + t1.y*b1.z + t1.z*b2.z + t1.w*b3.z;
                acc[1].w += t1.x*b0.w + t1.y*b1.w + t1.z*b2.w + t1.w*b3.w;
                acc[2].x += t2.x*b0.x + t2.y*b1.x + t2.z*b2.x + t2.w*b3.x;
                acc[2].y += t2.x*b0.y + t2.y*b1.y + t2.z*b2.y + t2.w*b3.y;
                acc[2].z += t2.x*b0.z + t2.y*b1.z + t2.z*b2.z + t2.w*b3.z;
                acc[2].w += t2.x*b0.w + t2.y*b1.w + t2.z*b2.w + t2.w*b3.w;
                acc[3].x += t3.x*b0.x + t3.y*b1.x + t3.z*b2.x + t3.w*b3.x;
                acc[3].y += t3.x*b0.y + t3.y*b1.y + t3.z*b2.y + t3.w*b3.y;
                acc[3].z += t3.x*b0.z + t3.y*b1.z + t3.z*b2.z + t3.w*b3.z;
                acc[3].w += t3.x*b0.w + t3.y*b1.w + t3.z*b2.w + t3.w*b3.w;
            }
            #pragma unroll
            for (int x = 0; x < 4; ++x) {
                ushort4 o; o.x = f2bf(acc[x].x); o.y = f2bf(acc[x].y);
                o.z = f2bf(acc[x].z); o.w = f2bf(acc[x].w);
                *(ushort4*)(Up + (i0+x)*DV_ + c0) = o;
            }
        }
        unsigned short* Kp = KCDw + (size_t)cid*(CK_*DK_);
        for (int tt = tid; tt < 512; tt += 256) {
            const int i0 = (tt >> 5) << 2, c0 = (tt & 31) << 2;
            const int xi = i0 & 28;
            float4 acc[4];
            #pragma unroll
            for (int x = 0; x < 4; ++x) {
                float wi = cL[i0+x];
                float4 kv = *(float4*)&kn[i0+x][c0 ^ xi];
                acc[x].x = kv.x*wi; acc[x].y = kv.y*wi; acc[x].z = kv.z*wi; acc[x].w = kv.w*wi;
            }
            for (int j0 = 0; j0 <= i0; j0 += 4) {
                const int xj = j0 & 28;
                float w0 = cL[j0], w1 = cL[j0+1], w2 = cL[j0+2], w3 = cL[j0+3];
                float4 t0 = *(float4*)&T[i0][j0],   t1 = *(float4*)&T[i0+1][j0];
                float4 t2 = *(float4*)&T[i0+2][j0], t3 = *(float4*)&T[i0+3][j0];
                float4 b0 = *(float4*)&kn[j0  ][c0 ^ xj], b1 = *(float4*)&kn[j0+1][c0 ^ xj];
                float4 b2 = *(float4*)&kn[j0+2][c0 ^ xj], b3 = *(float4*)&kn[j0+3][c0 ^ xj];
                b0.x*=w0; b0.y*=w0; b0.z*=w0; b0.w*=w0;
                b1.x*=w1; b1.y*=w1; b1.z*=w1; b1.w*=w1;
                b2.x*=w2; b2.y*=w2; b2.z*=w2; b2.w*=w2;
                b3.x*=w3; b3.y*=w3; b3.z*=w3; b3.w*=w3;
                acc[0].x += t0.x*b0.x + t0.y*b1.x + t0.z*b2.x + t0.w*b3.x;
                acc[0].y += t0.x*b0.y + t0.y*b1.y + t0.z*b2.y + t0.w*b3.y;
                acc[0].z += t0.x*b0.z + t0.y*b1.z + t0.z*b2.z + t0.w*b3.z;
                acc[0].w += t0.x*b0.w + t0.y*b1.w + t0.z*b2.w + t0.w*b3.w;
                acc[1].x += t1.x*b0.x + t1.y*b1.x + t1.z*b2.x + t1.w*b3.x;
                acc[1].y += t1.x*b0.y + t1.y*b1.y + t1.z*b2.y + t1.w*b3.y;
                acc[1].z += t1.x*b0.z + t1.y*b1.z + t1.z*b2.z + t1.w*b3.z;
                acc[1].w += t1.x*b0.w + t1.y*b1.w + t1.z*b2.w + t1.w*b3.w;
                acc[2].x += t2.x*b0.x + t2.y*b1.x + t2.z*b2.x + t2.w*b3.x;
                acc[2].y += t2.x*b0.y + t2.y*b1.y + t2.z*b2.y + t2.w*b3.y;
                acc[2].z += t2.x*b0.z + t2.y*b1.z + t2.z*b2.z + t2.w*b3.z;
                acc[2].w += t2.x*b0.w + t2.y*b1.w + t2.z*b2.w + t2.w*b3.w;
                acc[3].x += t3.x*b0.x + t3.y*b1.x + t3.z*b2.x + t3.w*b3.x;
                acc[3].y += t3.x*b0.y + t3.y*b1.y + t3.z*b2.y + t3.w*b3.y;
                acc[3].z += t3.x*b0.z + t3.y*b1.z + t3.z*b2.z + t3.w*b3.z;
                acc[3].w += t3.x*b0.w + t3.y*b1.w + t3.z*b2.w + t3.w*b3.w;
            }
            #pragma unroll
            for (int x = 0; x < 4; ++x) {
                ushort4 o; o.x = f2bf(acc[x].x); o.y = f2bf(acc[x].y);
                o.z = f2bf(acc[x].z); o.w = f2bf(acc[x].w);
                *(ushort4*)(Kp + (i0+x)*DK_ + c0) = o;
            }
        }
    }
    __syncthreads();

    // F: stage raw q -> f16 (scale folded into epilogue)
    #pragma unroll
    for (int i = 0; i < 8; ++i) {
        int idx4 = tid + 256*i;
        int r = idx4 >> 5, c0 = (idx4 & 31) << 2;
        f4toh4(&bufh[r][c0], *(const float4*)(Q + (size_t)(rowbase + r*H_)*DK_ + c0));
    }
    __syncthreads();
    // G: q row norms (QSCALE folded); RQ
    if (tid < 64) {
        float s = 0.f;
        #pragma unroll
        for (int c = 0; c < 128; c += 4) { float4 x = h4tof4(&bufh[tid][c]); s += DOT4(x,x); }
        float r_ = rsqrtf(s + 1e-6f)*QSCALE;
        rn[tid] = r_;
        RQw[cid*64 + tid] = r_*epos[tid];
    }
    __syncthreads();

    // H: attn = tril(q@k^T * decay) -> bf16
    {
        unsigned short* Ap = ATTNw + (size_t)cid*(CK_*CK_);
        const int i0 = (tid >> 4) << 2, j0 = (tid & 15) << 2;
        const int xj = j0 & 28;
        float acc[4][4] = {};
        if (j0 <= i0) {
            for (int c = 0; c < 128; c += 4) {
                float4 a0 = h4tof4(&bufh[i0  ][c]), a1 = h4tof4(&bufh[i0+1][c]);
                float4 a2 = h4tof4(&bufh[i0+2][c]), a3 = h4tof4(&bufh[i0+3][c]);
                float4 b0 = *(float4*)&kn[j0  ][c ^ xj], b1 = *(float4*)&kn[j0+1][c ^ xj];
                float4 b2 = *(float4*)&kn[j0+2][c ^ xj], b3 = *(float4*)&kn[j0+3][c ^ xj];
                acc[0][0]+=DOT4(a0,b0); acc[0][1]+=DOT4(a0,b1); acc[0][2]+=DOT4(a0,b2); acc[0][3]+=DOT4(a0,b3);
                acc[1][0]+=DOT4(a1,b0); acc[1][1]+=DOT4(a1,b1); acc[1][2]+=DOT4(a1,b2); acc[1][3]+=DOT4(a1,b3);
                acc[2][0]+=DOT4(a2,b0); acc[2][1]+=DOT4(a2,b1); acc[2][2]+=DOT4(a2,b2); acc[2][3]+=DOT4(a2,b3);
                acc[3][0]+=DOT4(a3,b0); acc[3][1]+=DOT4(a3,b1); acc[3][2]+=DOT4(a3,b2); acc[3][3]+=DOT4(a3,b3);
            }
        }
        #pragma unroll
        for (int x = 0; x < 4; ++x) {
            ushort4 o;
            int i = i0+x;
            float fi = rn[i]*epos[i];
            float v0 = (j0   <= i) ? acc[x][0]*fi*cR[j0]   : 0.f;
            float v1 = (j0+1 <= i) ? acc[x][1]*fi*cR[j0+1] : 0.f;
            float v2 = (j0+2 <= i) ? acc[x][2]*fi*cR[j0+2] : 0.f;
            float v3 = (j0+3 <= i) ? acc[x][3]*fi*cR[j0+3] : 0.f;
            o.x = f2bf(v0); o.y = f2bf(v1); o.z = f2bf(v2); o.w = f2bf(v3);
            *(ushort4*)(Ap + i*CK_ + j0) = o;
        }
    }
}

// ---------------- Phase 2: state recurrence (512 blocks = bh x 16 v-slices of 8) --------
// Finer v-split: LDS 74.9 KB -> 2 blocks/CU = 16 waves/CU; two blocks overlap each
// other's barrier/dependency stalls. Per-chunk per-block work halves.
#define P2_LOAD(nn) do { \
    const int cid_ = bh*NC_ + (nn); \
    const int rb_ = (b*S_ + (nn)*CK_)*H_ + h; \
    _Pragma("unroll") \
    for (int i = 0; i < 4; ++i) { \
        int idx4 = tid + 512*i; \
        int r = idx4 >> 5, c0 = (idx4 & 31)*4; \
        (void)c0; \
        pk[i]  = *(const float4*)(K + (size_t)(rb_ + r*H_)*DK_ + ((idx4 & 31)*4)); \
        pc[i]  = ((const uint2*)(KCDw + (size_t)cid_*8192))[idx4]; \
        prk[i] = RKw[cid_*64 + r]; \
    } \
    pu = Uw[(size_t)cid_*8192 + rg*128 + v0 + w0]; \
} while(0)

__global__ __launch_bounds__(512) void dr_phase2(
    const float* __restrict__ K,
    const unsigned short* __restrict__ Uw, const unsigned short* __restrict__ KCDw,
    const float* __restrict__ RKw, const float* __restrict__ EGw,
    unsigned short* __restrict__ STw)
{
    __shared__ float kc[64][132];    // kcd fp32
    __shared__ float kd[64][132];    // k_norm * exp(g_last - gcs)
    __shared__ float stT[8][132];    // state^T slice: stT[v][k]
    __shared__ float vnr[64][12];    // v_new slice

    const int tid = threadIdx.x;
    const int vs = blockIdx.x & 15, bh = blockIdx.x >> 4;
    const int h = bh & (H_-1), b = bh >> 4;
    const int v0 = vs*8;

    for (int i = tid; i < 8*132; i += 512) (&stT[0][0])[i] = 0.f;

    const int rg  = tid >> 3;            // vn row (0..63)
    const int w0  = tid & 7;             // vn col (0..7)
    const int wq  = tid >> 6;            // update: stT row (0..7, wave-uniform)
    const int k0s = (tid & 63) * 2;      // update: col pair
    const int srow = tid >> 6, scol = (tid & 63) * 2;   // ST store map

    float4 pk[4]; uint2 pc[4]; float prk[4]; unsigned short pu;
    P2_LOAD(0);
    __syncthreads();

    for (int n = 0; n < NC_; ++n) {
        const int cid = bh*NC_ + n;

        // write prefetched chunk n into LDS
        #pragma unroll
        for (int i = 0; i < 4; ++i) {
            int idx4 = tid + 512*i;
            int r = idx4 >> 5, c0 = (idx4 & 31)*4;
            float4 f;
            f.x = bf2f((unsigned short)(pc[i].x & 0xffff));
            f.y = bf2f((unsigned short)(pc[i].x >> 16));
            f.z = bf2f((unsigned short)(pc[i].y & 0xffff));
            f.w = bf2f((unsigned short)(pc[i].y >> 16));
            *(float4*)&kc[r][c0] = f;
            float4 kv = pk[i];
            kv.x *= prk[i]; kv.y *= prk[i]; kv.z *= prk[i]; kv.w *= prk[i];
            *(float4*)&kd[r][c0] = kv;
        }
        const float u0 = bf2f(pu);

        // store state entering chunk n (pre-update) for phase 3
        {
            float2 s = *(float2*)&stT[srow][scol];
            unsigned p = (unsigned)f2bf(s.x) | ((unsigned)f2bf(s.y) << 16);
            *(unsigned*)(STw + ((size_t)cid*128 + v0 + srow)*128 + scol) = p;
        }
        __syncthreads();

        if (n+1 < NC_) P2_LOAD(n+1);    // overlap HBM latency with compute below
        const float a_dec = EGw[cid];

        // vn = u - kc @ stT^T   (1 elem per thread: row rg, col w0)
        {
            float s0 = u0;
            for (int k0 = 0; k0 < 128; k0 += 8) {
                float4 a0 = *(float4*)&kc[rg][k0];
                float4 a1 = *(float4*)&kc[rg][k0+4];
                float4 b0 = *(float4*)&stT[w0][k0];
                float4 b1 = *(float4*)&stT[w0][k0+4];
                s0 -= DOT4(a0,b0) + DOT4(a1,b1);
            }
            vnr[rg][w0] = s0;
        }
        __syncthreads();

        // stT = a*stT + vn^T @ kd   (float2 per thread; wq wave-uniform)
        {
            float2 acc = *(float2*)&stT[wq][k0s];
            acc.x *= a_dec; acc.y *= a_dec;
            for (int r = 0; r < 64; ++r) {
                float vv = vnr[r][wq];
                float2 kv = *(float2*)&kd[r][k0s];
                acc.x += vv*kv.x; acc.y += vv*kv.y;
            }
            *(float2*)&stT[wq][k0s] = acc;
        }
        __syncthreads();
    }
}

// ---------------- Phase 3: outputs (4096 blocks = chunk x Dv-half) ----------------
// (unchanged)
__global__ __launch_bounds__(256) void dr_phase3(
    const float* __restrict__ Q,
    const unsigned short* __restrict__ Uw, const unsigned short* __restrict__ KCDw,
    const unsigned short* __restrict__ ATTNw, const unsigned short* __restrict__ STw,
    const float* __restrict__ RQw, float* __restrict__ Out)
{
    __shared__ __align__(16) __half         qh[64][136];  // q*rq*exp(gcs) (f16, swz)
    __shared__ __align__(16) unsigned short kch[64][136]; // kcd bf16 raw (swz)
    __shared__ __align__(16) unsigned short sth[64][136]; // state^T bf16 raw (swz)
    __shared__ __align__(16) unsigned short ath[64][72];  // attn bf16 raw (swz)
    __shared__ float vnT[64][68];                         // v_new^T f32 (swz)

    const int tid = threadIdx.x;
    const int half = blockIdx.x & 1;
    const int cid = blockIdx.x >> 1;
    const int n = cid & (NC_-1), bh = cid >> 6;
    const int h = bh & (H_-1), b = bh >> 4;
    const int rowbase = (b*S_ + n*CK_)*H_ + h;
    const int vbase = half*64;

    #pragma unroll
    for (int i = 0; i < 8; ++i) {
        int idx4 = tid + 256*i;
        int r = idx4 >> 5, c0 = (idx4 & 31)*4;
        float rq = RQw[cid*64 + r];
        float4 qv = *(const float4*)(Q + (size_t)(rowbase + r*H_)*DK_ + c0);
        qv.x *= rq; qv.y *= rq; qv.z *= rq; qv.w *= rq;
        f4toh4(&qh[r][SWH(c0, r)], qv);
        uint2 kcv = ((const uint2*)(KCDw + (size_t)cid*8192))[idx4];
        *(uint2*)&kch[r][SWH(c0, r)] = kcv;
        uint2 stv = ((const uint2*)(STw + ((size_t)cid*128 + vbase)*128))[idx4];
        *(uint2*)&sth[r][SWH(c0, r)] = stv;
    }
    #pragma unroll
    for (int i = 0; i < 4; ++i) {
        int idx4 = tid + 256*i;
        int r = idx4 >> 4, j0 = (idx4 & 15)*4;
        uint2 av = ((const uint2*)(ATTNw + (size_t)cid*4096))[idx4];
        *(uint2*)&ath[r][SWH(j0, r)] = av;
    }
    __syncthreads();

    const int r0 = (tid >> 4)*4, v4 = (tid & 15)*4;

    // vn = u - kc @ state  -> vnT[v][r] (f32, swizzled)
    {
        float4 acc[4];   // acc[x].{x,y,z,w} = vn[r0+x][v4+0..3]
        #pragma unroll
        for (int x = 0; x < 4; ++x) {
            ushort4 uv = *(const ushort4*)(Uw + (size_t)cid*8192 + (r0+x)*128 + vbase + v4);
            acc[x].x = bf2f(uv.x); acc[x].y = bf2f(uv.y); acc[x].z = bf2f(uv.z); acc[x].w = bf2f(uv.w);
        }
        for (int k0 = 0; k0 < 128; k0 += 8) {
            f8 A[4], Bv[4];
            #pragma unroll
            for (int x = 0; x < 4; ++x) A[x]  = unp_bf16x8(*(const uint4*)&kch[r0+x][SWH(k0, r0+x)]);
            #pragma unroll
            for (int y = 0; y < 4; ++y) Bv[y] = unp_bf16x8(*(const uint4*)&sth[v4+y][SWH(k0, v4+y)]);
            #pragma unroll
            for (int x = 0; x < 4; ++x) {
                acc[x].x -= DOT4(A[x].lo, Bv[0].lo) + DOT4(A[x].hi, Bv[0].hi);
                acc[x].y -= DOT4(A[x].lo, Bv[1].lo) + DOT4(A[x].hi, Bv[1].hi);
                acc[x].z -= DOT4(A[x].lo, Bv[2].lo) + DOT4(A[x].hi, Bv[2].hi);
                acc[x].w -= DOT4(A[x].lo, Bv[3].lo) + DOT4(A[x].hi, Bv[3].hi);
            }
        }
        #pragma unroll
        for (int x = 0; x < 4; ++x) {
            vnT[v4+0][SWV(r0+x, v4+0)] = acc[x].x;
            vnT[v4+1][SWV(r0+x, v4+1)] = acc[x].y;
            vnT[v4+2][SWV(r0+x, v4+2)] = acc[x].z;
            vnT[v4+3][SWV(r0+x, v4+3)] = acc[x].w;
        }
    }
    __syncthreads();

    // o = qg @ state + attn @ vn
    {
        float4 acc[4] = {};   // acc[x].{y} = o[r0+x][vbase+v4+y]
        for (int k0 = 0; k0 < 128; k0 += 8) {
            f8 A[4], Bv[4];
            #pragma unroll
            for (int x = 0; x < 4; ++x) A[x]  = unp_f16x8(*(const uint4*)&qh[r0+x][SWH(k0, r0+x)]);
            #pragma unroll
            for (int y = 0; y < 4; ++y) Bv[y] = unp_bf16x8(*(const uint4*)&sth[v4+y][SWH(k0, v4+y)]);
            #pragma unroll
            for (int x = 0; x < 4; ++x) {
                acc[x].x += DOT4(A[x].lo, Bv[0].lo) + DOT4(A[x].hi, Bv[0].hi);
                acc[x].y += DOT4(A[x].lo, Bv[1].lo) + DOT4(A[x].hi, Bv[1].hi);
                acc[x].z += DOT4(A[x].lo, Bv[2].lo) + DOT4(A[x].hi, Bv[2].hi);
                acc[x].w += DOT4(A[x].lo, Bv[3].lo) + DOT4(A[x].hi, Bv[3].hi);
            }
        }
        for (int j0 = 0; j0 <= r0+3; j0 += 8) {
            f8 A[4];
            #pragma unroll
            for (int x = 0; x < 4; ++x) A[x] = unp_bf16x8(*(const uint4*)&ath[r0+x][SWH(j0, r0+x)]);
            float4 bLo[4], bHi[4];
            #pragma unroll
            for (int y = 0; y < 4; ++y) {
                bLo[y] = *(const float4*)&vnT[v4+y][SWV(j0,   v4+y)];
                bHi[y] = *(const float4*)&vnT[v4+y][SWV(j0+4, v4+y)];
            }
            #pragma unroll
            for (int x = 0; x < 4; ++x) {
                acc[x].x += DOT4(A[x].lo, bLo[0]) + DOT4(A[x].hi, bHi[0]);
                acc[x].y += DOT4(A[x].lo, bLo[1]) + DOT4(A[x].hi, bHi[1]);
                acc[x].z += DOT4(A[x].lo, bLo[2]) + DOT4(A[x].hi, bHi[2]);
                acc[x].w += DOT4(A[x].lo, bLo[3]) + DOT4(A[x].hi, bHi[3]);
            }
        }
        #pragma unroll
        for (int x = 0; x < 4; ++x)
            *(float4*)(Out + (size_t)(rowbase + (r0+x)*H_)*DV_ + vbase + v4) = acc[x];
    }
}

extern "C" void kernel_launch(void* const* d_in, const int* in_sizes, int n_in,
                              void* d_out, int out_size, void* d_ws, size_t ws_size,
                              hipStream_t stream) {
    (void)in_sizes; (void)n_in; (void)out_size; (void)ws_size;
    const float* Q  = (const float*)d_in[0];
    const float* K  = (const float*)d_in[1];
    const float* V  = (const float*)d_in[2];
    const float* G  = (const float*)d_in[3];
    const float* Bt = (const float*)d_in[4];
    float* Out = (float*)d_out;

    // ws layout: U bf16 | KCD bf16 | ATTN bf16 | ST bf16 | RQ f32 | RK f32 | EG f32
    unsigned short* Uw    = (unsigned short*)d_ws;
    unsigned short* KCDw  = Uw    + (size_t)2048*64*128;
    unsigned short* ATTNw = KCDw  + (size_t)2048*64*128;
    unsigned short* STw   = ATTNw + (size_t)2048*64*64;
    float* RQw = (float*)(STw + (size_t)2048*128*128);
    float* RKw = RQw + 2048*64;
    float* EGw = RKw + 2048*64;

    dr_phase1<<<2048, 256, 0, stream>>>(Q, K, V, G, Bt, Uw, KCDw, ATTNw, RQw, RKw, EGw);
    dr_phase2<<<512, 512, 0, stream>>>(K, Uw, KCDw, RKw, EGw, STw);
    dr_phase3<<<4096, 256, 0, stream>>>(Q, Uw, KCDw, ATTNw, STw, RQw, Out);
}

// Round 4
// 813.188 us; speedup vs baseline: 1.1489x; 1.1489x over previous
//
#include <hip/hip_runtime.h>
#include <hip/hip_fp16.h>

#define B_   2
#define S_   4096
#define H_   16
#define DK_  128
#define DV_  128
#define CK_  64
#define NC_  (S_/CK_)            // 64 chunks per sequence
#define QSCALE 0.08838834764831845f   // 128^-0.5

#define DOT4(a,b) ((a).x*(b).x + (a).y*(b).y + (a).z*(b).z + (a).w*(b).w)

// 16B-granule XOR swizzles: kill 8-way bank conflicts on multi-row reads.
// SWH: arrays of 16-bit elems (granule = 8 elems). SWV: f32 arrays (granule = 4 elems).
#define SWH(c, r) (((((c) >> 3) ^ (((r) >> 2) & 7)) << 3) | ((c) & 7))
#define SWV(c, r) (((((c) >> 2) ^ (((r) >> 2) & 7)) << 2) | ((c) & 3))

static __device__ __forceinline__ unsigned short f2bf(float x) {
    unsigned u = __float_as_uint(x);
    unsigned r = u + 0x7fffu + ((u >> 16) & 1u);
    return (unsigned short)(r >> 16);
}
static __device__ __forceinline__ float bf2f(unsigned short h) {
    return __uint_as_float(((unsigned)h) << 16);
}
static __device__ __forceinline__ float4 h4tof4(const __half* p) {
    float2 f01 = __half22float2(*(const __half2*)p);
    float2 f23 = __half22float2(*(const __half2*)(p + 2));
    return make_float4(f01.x, f01.y, f23.x, f23.y);
}
static __device__ __forceinline__ void f4toh4(__half* p, float4 v) {
    *(__half2*)p       = __floats2half2_rn(v.x, v.y);
    *(__half2*)(p + 2) = __floats2half2_rn(v.z, v.w);
}

struct f8 { float4 lo, hi; };
// 8 bf16 (uint4) -> 8 f32: 2 VALU ops per uint (shl / and)
static __device__ __forceinline__ f8 unp_bf16x8(uint4 u) {
    f8 r;
    r.lo.x = __uint_as_float(u.x << 16); r.lo.y = __uint_as_float(u.x & 0xffff0000u);
    r.lo.z = __uint_as_float(u.y << 16); r.lo.w = __uint_as_float(u.y & 0xffff0000u);
    r.hi.x = __uint_as_float(u.z << 16); r.hi.y = __uint_as_float(u.z & 0xffff0000u);
    r.hi.z = __uint_as_float(u.w << 16); r.hi.w = __uint_as_float(u.w & 0xffff0000u);
    return r;
}
static __device__ __forceinline__ f8 unp_f16x8(uint4 u) {
    f8 r;
    float2 a = __half22float2(*(__half2*)&u.x), b = __half22float2(*(__half2*)&u.y);
    float2 c = __half22float2(*(__half2*)&u.z), d = __half22float2(*(__half2*)&u.w);
    r.lo = make_float4(a.x, a.y, b.x, b.y);
    r.hi = make_float4(c.x, c.y, d.x, d.y);
    return r;
}

// ---------------- Phase 1: per-chunk (parallel over 2048 chunks) ----------------
// (unchanged)
__global__ __launch_bounds__(256) void dr_phase1(
    const float* __restrict__ Q, const float* __restrict__ K,
    const float* __restrict__ V, const float* __restrict__ G,
    const float* __restrict__ Bt,
    unsigned short* __restrict__ Uw, unsigned short* __restrict__ KCDw,
    unsigned short* __restrict__ ATTNw,
    float* __restrict__ RQw, float* __restrict__ RKw, float* __restrict__ EGw)
{
    __shared__ float kn[64][132];                 // raw k, swizzled
    __shared__ __align__(16) __half bufh[64][136]; // v*beta, then raw q (f16)
    __shared__ float T[64][68];
    __shared__ float tmp[32][36];                 // blocked-inverse scratch
    __shared__ float bet[64], rn[64], epos[64], eneg[64], cL[64], cR[64];

    const int tid = threadIdx.x;
    const int cid = blockIdx.x;
    const int n   = cid & (NC_ - 1);
    const int bh  = cid >> 6;
    const int h   = bh & (H_ - 1);
    const int b   = bh >> 4;
    const int rowbase = (b*S_ + n*CK_)*H_ + h;

    // A: stage raw K (swizzled); wave0: shfl-scan of g, exps, beta
    #pragma unroll
    for (int i = 0; i < 8; ++i) {
        int idx4 = tid + 256*i;
        int r = idx4 >> 5, c0 = (idx4 & 31) << 2;
        *(float4*)&kn[r][c0 ^ (r & 28)] =
            *(const float4*)(K + (size_t)(rowbase + r*H_)*DK_ + c0);
    }
    if (tid < 64) {
        float g = G[rowbase + tid*H_];
        #pragma unroll
        for (int off = 1; off < 64; off <<= 1) {
            float o = __shfl_up(g, off, 64);
            if (tid >= off) g += o;
        }
        float ep = expf(g);
        epos[tid] = ep;
        eneg[tid] = expf(-g);
        bet[tid]  = Bt[rowbase + tid*H_];
        if (tid == 63) EGw[cid] = ep;
    }
    __syncthreads();

    // B: stage v*beta -> f16; k row norms -> rn, cL, cR, RK
    #pragma unroll
    for (int i = 0; i < 8; ++i) {
        int idx4 = tid + 256*i;
        int r = idx4 >> 5, c0 = (idx4 & 31) << 2;
        float bb = bet[r];
        float4 vv = *(const float4*)(V + (size_t)(rowbase + r*H_)*DV_ + c0);
        vv.x *= bb; vv.y *= bb; vv.z *= bb; vv.w *= bb;
        f4toh4(&bufh[r][c0], vv);
    }
    if (tid < 64) {
        const int xr = tid & 28;
        float s = 0.f;
        #pragma unroll
        for (int c = 0; c < 128; c += 4) { float4 x = *(float4*)&kn[tid][c ^ xr]; s += DOT4(x,x); }
        float r_ = rsqrtf(s + 1e-6f);
        rn[tid] = r_;
        RKw[cid*64 + tid] = r_*epos[63]*eneg[tid];
        cL[tid] = bet[tid]*epos[tid]*r_;
        cR[tid] = eneg[tid]*r_;
    }
    __syncthreads();

    // C: T = -strict_lower( cL(i)*cR(j) * (kraw_i . kraw_j) )
    {
        const int i0 = (tid >> 4) << 2, j0 = (tid & 15) << 2;
        const int xi = i0 & 28, xj = j0 & 28;
        float acc[4][4] = {};
        if (j0 <= i0) {
            for (int c = 0; c < 128; c += 4) {
                float4 a0 = *(float4*)&kn[i0  ][c ^ xi], a1 = *(float4*)&kn[i0+1][c ^ xi];
                float4 a2 = *(float4*)&kn[i0+2][c ^ xi], a3 = *(float4*)&kn[i0+3][c ^ xi];
                float4 b0 = *(float4*)&kn[j0  ][c ^ xj], b1 = *(float4*)&kn[j0+1][c ^ xj];
                float4 b2 = *(float4*)&kn[j0+2][c ^ xj], b3 = *(float4*)&kn[j0+3][c ^ xj];
                acc[0][0]+=DOT4(a0,b0); acc[0][1]+=DOT4(a0,b1); acc[0][2]+=DOT4(a0,b2); acc[0][3]+=DOT4(a0,b3);
                acc[1][0]+=DOT4(a1,b0); acc[1][1]+=DOT4(a1,b1); acc[1][2]+=DOT4(a1,b2); acc[1][3]+=DOT4(a1,b3);
                acc[2][0]+=DOT4(a2,b0); acc[2][1]+=DOT4(a2,b1); acc[2][2]+=DOT4(a2,b2); acc[2][3]+=DOT4(a2,b3);
                acc[3][0]+=DOT4(a3,b0); acc[3][1]+=DOT4(a3,b1); acc[3][2]+=DOT4(a3,b2); acc[3][3]+=DOT4(a3,b3);
            }
        }
        #pragma unroll
        for (int x = 0; x < 4; ++x) {
            float fi = cL[i0+x];
            #pragma unroll
            for (int y = 0; y < 4; ++y) {
                int i = i0+x, j = j0+y;
                T[i][j] = (i > j) ? (-fi*cR[j]*acc[x][y]) : 0.f;
            }
        }
    }
    __syncthreads();

    // D1: copy diagonal 16x16 blocks (original -A) into tmp
    {
        float* tf = &tmp[0][0];
        for (int t = tid; t < 1024; t += 256) {
            int d = t >> 8, i = (t >> 4) & 15, j = t & 15;
            tf[t] = T[(d<<4) + i][(d<<4) + j];
        }
    }
    __syncthreads();
    // D2: invert each diagonal block in place, one thread per (block, column)
    if (tid < 64) {
        const float* Ad = &tmp[0][0] + ((tid >> 4) << 8);
        const int j = tid & 15, R = (tid >> 4) << 4;
        for (int i = j+1; i < 16; ++i) {
            float x = Ad[(i<<4) + j];
            for (int l = j+1; l < i; ++l) x += Ad[(i<<4) + l] * T[R+l][R+j];
            T[R+i][R+j] = x;
        }
    }
    __syncthreads();
    // D3: 16 -> 32 (two pairs). X21 = (I+X22) * T21 * (I+X11)
    {
        const int p = tid >> 7, rem = tid & 127, i = rem >> 3, j0 = (rem & 7) << 1;
        const int bb2 = p << 5;
        float x0 = T[bb2+16+i][bb2+j0], x1 = T[bb2+16+i][bb2+j0+1];
        for (int l = j0+1; l < 16; ++l) {
            float a = T[bb2+16+i][bb2+l];
            x0 += a * T[bb2+l][bb2+j0];
            if (l > j0+1) x1 += a * T[bb2+l][bb2+j0+1];
        }
        tmp[(p<<4)+i][j0] = x0; tmp[(p<<4)+i][j0+1] = x1;
        __syncthreads();
        float y0 = tmp[(p<<4)+i][j0], y1 = tmp[(p<<4)+i][j0+1];
        for (int l = 0; l < i; ++l) {
            float a = T[bb2+16+i][bb2+16+l];
            y0 += a * tmp[(p<<4)+l][j0];
            y1 += a * tmp[(p<<4)+l][j0+1];
        }
        T[bb2+16+i][bb2+j0] = y0; T[bb2+16+i][bb2+j0+1] = y1;
    }
    __syncthreads();
    // D4: 32 -> 64
    {
        const int i = tid >> 3, j0 = (tid & 7) << 2;
        float x0 = T[32+i][j0], x1 = T[32+i][j0+1], x2 = T[32+i][j0+2], x3 = T[32+i][j0+3];
        for (int l = j0+1; l < 32; ++l) {
            float a = T[32+i][l];
            x0 += a * T[l][j0];
            if (l > j0+1) x1 += a * T[l][j0+1];
            if (l > j0+2) x2 += a * T[l][j0+2];
            if (l > j0+3) x3 += a * T[l][j0+3];
        }
        tmp[i][j0] = x0; tmp[i][j0+1] = x1; tmp[i][j0+2] = x2; tmp[i][j0+3] = x3;
        __syncthreads();
        float y0 = tmp[i][j0], y1 = tmp[i][j0+1], y2 = tmp[i][j0+2], y3 = tmp[i][j0+3];
        for (int l = 0; l < i; ++l) {
            float a = T[32+i][32+l];
            y0 += a * tmp[l][j0];   y1 += a * tmp[l][j0+1];
            y2 += a * tmp[l][j0+2]; y3 += a * tmp[l][j0+3];
        }
        T[32+i][j0] = y0; T[32+i][j0+1] = y1; T[32+i][j0+2] = y2; T[32+i][j0+3] = y3;
    }
    __syncthreads();

    // E: U = (I+T) @ (v*beta),  KCD = (I+T) @ (k*beta*exp(gcs))  -> bf16
    {
        unsigned short* Up = Uw + (size_t)cid*(CK_*DV_);
        for (int tt = tid; tt < 512; tt += 256) {
            const int i0 = (tt >> 5) << 2, c0 = (tt & 31) << 2;
            float4 acc[4];
            #pragma unroll
            for (int x = 0; x < 4; ++x) acc[x] = h4tof4(&bufh[i0+x][c0]);
            for (int j0 = 0; j0 <= i0; j0 += 4) {
                float4 t0 = *(float4*)&T[i0][j0],   t1 = *(float4*)&T[i0+1][j0];
                float4 t2 = *(float4*)&T[i0+2][j0], t3 = *(float4*)&T[i0+3][j0];
                float4 b0 = h4tof4(&bufh[j0][c0]),   b1 = h4tof4(&bufh[j0+1][c0]);
                float4 b2 = h4tof4(&bufh[j0+2][c0]), b3 = h4tof4(&bufh[j0+3][c0]);
                acc[0].x += t0.x*b0.x + t0.y*b1.x + t0.z*b2.x + t0.w*b3.x;
                acc[0].y += t0.x*b0.y + t0.y*b1.y + t0.z*b2.y + t0.w*b3.y;
                acc[0].z += t0.x*b0.z + t0.y*b1.z + t0.z*b2.z + t0.w*b3.z;
                acc[0].w += t0.x*b0.w + t0.y*b1.w + t0.z*b2.w + t0.w*b3.w;
                acc[1].x += t1.x*b0.x + t1.y*b1.x + t1.z*b2.x + t1.w*b3.x;
                acc[1].y += t1.x*b0.y + t1.y*b1.y + t1.z*b2.y + t1.w*b3.y;
                acc[1].z += t1.x*b0.z + t1.y*b1.z + t1.z*b2.z + t1.w*b3.z;
                acc[1].w += t1.x*b0.w + t1.y*b1.w + t1.z*b2.w + t1.w*b3.w;
                acc[2].x += t2.x*b0.x + t2.y*b1.x + t2.z*b2.x + t2.w*b3.x;
                acc[2].y += t2.x*b0.y + t2.y*b1.y + t2.z*b2.y + t2.w*b3.y;
                acc[2].z += t2.x*b0.z + t2.y*b1.z + t2.z*b2.z + t2.w*b3.z;
                acc[2].w += t2.x*b0.w + t2.y*b1.w + t2.z*b2.w + t2.w*b3.w;
                acc[3].x += t3.x*b0.x + t3.y*b1.x + t3.z*b2.x + t3.w*b3.x;
                acc[3].y += t3.x*b0.y + t3.y*b1.y + t3.z*b2.y + t3.w*b3.y;
                acc[3].z += t3.x*b0.z + t3.y*b1.z + t3.z*b2.z + t3.w*b3.z;
                acc[3].w += t3.x*b0.w + t3.y*b1.w + t3.z*b2.w + t3.w*b3.w;
            }
            #pragma unroll
            for (int x = 0; x < 4; ++x) {
                ushort4 o; o.x = f2bf(acc[x].x); o.y = f2bf(acc[x].y);
                o.z = f2bf(acc[x].z); o.w = f2bf(acc[x].w);
                *(ushort4*)(Up + (i0+x)*DV_ + c0) = o;
            }
        }
        unsigned short* Kp = KCDw + (size_t)cid*(CK_*DK_);
        for (int tt = tid; tt < 512; tt += 256) {
            const int i0 = (tt >> 5) << 2, c0 = (tt & 31) << 2;
            const int xi = i0 & 28;
            float4 acc[4];
            #pragma unroll
            for (int x = 0; x < 4; ++x) {
                float wi = cL[i0+x];
                float4 kv = *(float4*)&kn[i0+x][c0 ^ xi];
                acc[x].x = kv.x*wi; acc[x].y = kv.y*wi; acc[x].z = kv.z*wi; acc[x].w = kv.w*wi;
            }
            for (int j0 = 0; j0 <= i0; j0 += 4) {
                const int xj = j0 & 28;
                float w0 = cL[j0], w1 = cL[j0+1], w2 = cL[j0+2], w3 = cL[j0+3];
                float4 t0 = *(float4*)&T[i0][j0],   t1 = *(float4*)&T[i0+1][j0];
                float4 t2 = *(float4*)&T[i0+2][j0], t3 = *(float4*)&T[i0+3][j0];
                float4 b0 = *(float4*)&kn[j0  ][c0 ^ xj], b1 = *(float4*)&kn[j0+1][c0 ^ xj];
                float4 b2 = *(float4*)&kn[j0+2][c0 ^ xj], b3 = *(float4*)&kn[j0+3][c0 ^ xj];
                b0.x*=w0; b0.y*=w0; b0.z*=w0; b0.w*=w0;
                b1.x*=w1; b1.y*=w1; b1.z*=w1; b1.w*=w1;
                b2.x*=w2; b2.y*=w2; b2.z*=w2; b2.w*=w2;
                b3.x*=w3; b3.y*=w3; b3.z*=w3; b3.w*=w3;
                acc[0].x += t0.x*b0.x + t0.y*b1.x + t0.z*b2.x + t0.w*b3.x;
                acc[0].y += t0.x*b0.y + t0.y*b1.y + t0.z*b2.y + t0.w*b3.y;
                acc[0].z += t0.x*b0.z + t0.y*b1.z + t0.z*b2.z + t0.w*b3.z;
                acc[0].w += t0.x*b0.w + t0.y*b1.w + t0.z*b2.w + t0.w*b3.w;
                acc[1].x += t1.x*b0.x + t1.y*b1.x + t1.z*b2.x + t1.w*b3.x;
                acc[1].y += t1.x*b0.y + t1.y*b1.y + t1.z*b2.y + t1.w*b3.y;
                acc[1].z += t1.x*b0.z + t1.y*b1.z + t1.z*b2.z + t1.w*b3.z;
                acc[1].w += t1.x*b0.w + t1.y*b1.w + t1.z*b2.w + t1.w*b3.w;
                acc[2].x += t2.x*b0.x + t2.y*b1.x + t2.z*b2.x + t2.w*b3.x;
                acc[2].y += t2.x*b0.y + t2.y*b1.y + t2.z*b2.y + t2.w*b3.y;
                acc[2].z += t2.x*b0.z + t2.y*b1.z + t2.z*b2.z + t2.w*b3.z;
                acc[2].w += t2.x*b0.w + t2.y*b1.w + t2.z*b2.w + t2.w*b3.w;
                acc[3].x += t3.x*b0.x + t3.y*b1.x + t3.z*b2.x + t3.w*b3.x;
                acc[3].y += t3.x*b0.y + t3.y*b1.y + t3.z*b2.y + t3.w*b3.y;
                acc[3].z += t3.x*b0.z + t3.y*b1.z + t3.z*b2.z + t3.w*b3.z;
                acc[3].w += t3.x*b0.w + t3.y*b1.w + t3.z*b2.w + t3.w*b3.w;
            }
            #pragma unroll
            for (int x = 0; x < 4; ++x) {
                ushort4 o; o.x = f2bf(acc[x].x); o.y = f2bf(acc[x].y);
                o.z = f2bf(acc[x].z); o.w = f2bf(acc[x].w);
                *(ushort4*)(Kp + (i0+x)*DK_ + c0) = o;
            }
        }
    }
    __syncthreads();

    // F: stage raw q -> f16 (scale folded into epilogue)
    #pragma unroll
    for (int i = 0; i < 8; ++i) {
        int idx4 = tid + 256*i;
        int r = idx4 >> 5, c0 = (idx4 & 31) << 2;
        f4toh4(&bufh[r][c0], *(const float4*)(Q + (size_t)(rowbase + r*H_)*DK_ + c0));
    }
    __syncthreads();
    // G: q row norms (QSCALE folded); RQ
    if (tid < 64) {
        float s = 0.f;
        #pragma unroll
        for (int c = 0; c < 128; c += 4) { float4 x = h4tof4(&bufh[tid][c]); s += DOT4(x,x); }
        float r_ = rsqrtf(s + 1e-6f)*QSCALE;
        rn[tid] = r_;
        RQw[cid*64 + tid] = r_*epos[tid];
    }
    __syncthreads();

    // H: attn = tril(q@k^T * decay) -> bf16
    {
        unsigned short* Ap = ATTNw + (size_t)cid*(CK_*CK_);
        const int i0 = (tid >> 4) << 2, j0 = (tid & 15) << 2;
        const int xj = j0 & 28;
        float acc[4][4] = {};
        if (j0 <= i0) {
            for (int c = 0; c < 128; c += 4) {
                float4 a0 = h4tof4(&bufh[i0  ][c]), a1 = h4tof4(&bufh[i0+1][c]);
                float4 a2 = h4tof4(&bufh[i0+2][c]), a3 = h4tof4(&bufh[i0+3][c]);
                float4 b0 = *(float4*)&kn[j0  ][c ^ xj], b1 = *(float4*)&kn[j0+1][c ^ xj];
                float4 b2 = *(float4*)&kn[j0+2][c ^ xj], b3 = *(float4*)&kn[j0+3][c ^ xj];
                acc[0][0]+=DOT4(a0,b0); acc[0][1]+=DOT4(a0,b1); acc[0][2]+=DOT4(a0,b2); acc[0][3]+=DOT4(a0,b3);
                acc[1][0]+=DOT4(a1,b0); acc[1][1]+=DOT4(a1,b1); acc[1][2]+=DOT4(a1,b2); acc[1][3]+=DOT4(a1,b3);
                acc[2][0]+=DOT4(a2,b0); acc[2][1]+=DOT4(a2,b1); acc[2][2]+=DOT4(a2,b2); acc[2][3]+=DOT4(a2,b3);
                acc[3][0]+=DOT4(a3,b0); acc[3][1]+=DOT4(a3,b1); acc[3][2]+=DOT4(a3,b2); acc[3][3]+=DOT4(a3,b3);
            }
        }
        #pragma unroll
        for (int x = 0; x < 4; ++x) {
            ushort4 o;
            int i = i0+x;
            float fi = rn[i]*epos[i];
            float v0 = (j0   <= i) ? acc[x][0]*fi*cR[j0]   : 0.f;
            float v1 = (j0+1 <= i) ? acc[x][1]*fi*cR[j0+1] : 0.f;
            float v2 = (j0+2 <= i) ? acc[x][2]*fi*cR[j0+2] : 0.f;
            float v3 = (j0+3 <= i) ? acc[x][3]*fi*cR[j0+3] : 0.f;
            o.x = f2bf(v0); o.y = f2bf(v1); o.z = f2bf(v2); o.w = f2bf(v3);
            *(ushort4*)(Ap + i*CK_ + j0) = o;
        }
    }
}

// ---------------- Phase 2: state recurrence (256 blocks = bh x 8 v-slices of 16) --------
// Wave-private state: wave w owns state rows {2w, 2w+1}; vn and the state update touch
// only those rows -> NO inter-wave sync except kc/kd staging. Double-buffered kc/kd ->
// exactly 1 barrier per chunk; waves drift freely between barriers.
// kc kept as raw bf16 in LDS (same bits as before -> identical numerics).
#define P2_LOAD(nn) do { \
    const int cid_ = bh*NC_ + (nn); \
    const int rb_ = (b*S_ + (nn)*CK_)*H_ + h; \
    _Pragma("unroll") \
    for (int i = 0; i < 4; ++i) { \
        int idx4 = tid + 512*i; \
        int r = idx4 >> 5; \
        pk[i]  = *(const float4*)(K + (size_t)(rb_ + r*H_)*DK_ + ((idx4 & 31)*4)); \
        pc[i]  = ((const uint2*)(KCDw + (size_t)cid_*8192))[idx4]; \
        prk[i] = RKw[cid_*64 + r]; \
    } \
    pu = *(const unsigned*)(Uw + (size_t)cid_*8192 + lane*128 + v0 + 2*w); \
} while(0)

__global__ __launch_bounds__(512) void dr_phase2(
    const float* __restrict__ K,
    const unsigned short* __restrict__ Uw, const unsigned short* __restrict__ KCDw,
    const float* __restrict__ RKw, const float* __restrict__ EGw,
    unsigned short* __restrict__ STw)
{
    __shared__ __align__(16) unsigned short kch[2][64][136]; // kcd raw bf16, SWH-swizzled
    __shared__ float kd[2][64][132];   // k_norm * exp(g_last - gcs), f32
    __shared__ float stT[16][132];     // state^T slice (row v owned by wave v>>1)
    __shared__ float vnw[8][64][2];    // per-wave vn columns (write by lane, read bcast)

    const int tid = threadIdx.x;
    const int vs = blockIdx.x & 7, bh = blockIdx.x >> 3;
    const int h = bh & (H_-1), b = bh >> 4;
    const int v0 = vs*16;
    const int w = tid >> 6, lane = tid & 63;
    const int lva = 2*w, lvb = 2*w + 1;          // this wave's state rows (local)
    const int c2 = 2*lane;                        // this lane's state col pair

    // init: state regs + LDS mirror (wave-private, no barrier needed)
    float2 sA = {0.f, 0.f}, sB = {0.f, 0.f};
    *(float2*)&stT[lva][c2] = sA;
    *(float2*)&stT[lvb][c2] = sB;

    float4 pk[4]; uint2 pc[4]; float prk[4]; unsigned pu;
    P2_LOAD(0);

    int cur = 0;
    for (int n = 0; n < NC_; ++n) {
        const int cid = bh*NC_ + n;
        const float u0 = bf2f((unsigned short)(pu & 0xffff));
        const float u1 = bf2f((unsigned short)(pu >> 16));

        // stage chunk n into buf[cur] (disjoint from buf[cur^1] others may still read)
        #pragma unroll
        for (int i = 0; i < 4; ++i) {
            int idx4 = tid + 512*i;
            int r = idx4 >> 5, c0 = (idx4 & 31)*4;
            *(uint2*)&kch[cur][r][SWH(c0, r)] = pc[i];
            float4 kv = pk[i];
            kv.x *= prk[i]; kv.y *= prk[i]; kv.z *= prk[i]; kv.w *= prk[i];
            *(float4*)&kd[cur][r][c0] = kv;
        }
        if (n+1 < NC_) P2_LOAD(n+1);     // issue next-chunk loads; land during compute
        __syncthreads();                  // buf[cur] ready for everyone

        // store pre-update state (entering chunk n) for phase 3, from regs
        {
            unsigned pA = (unsigned)f2bf(sA.x) | ((unsigned)f2bf(sA.y) << 16);
            unsigned pB = (unsigned)f2bf(sB.x) | ((unsigned)f2bf(sB.y) << 16);
            size_t base = ((size_t)cid*128 + v0)*128;
            *(unsigned*)(STw + base + (size_t)lva*128 + c2) = pA;
            *(unsigned*)(STw + base + (size_t)lvb*128 + c2) = pB;
        }

        // vn[lane][lva], vn[lane][lvb] = u - kc[lane,:] . stT[{lva,lvb},:]
        float vA = u0, vB = u1;
        for (int k0 = 0; k0 < 128; k0 += 8) {
            f8 a = unp_bf16x8(*(const uint4*)&kch[cur][lane][SWH(k0, lane)]);
            float4 pa0 = *(const float4*)&stT[lva][k0], pa1 = *(const float4*)&stT[lva][k0+4];
            float4 pb0 = *(const float4*)&stT[lvb][k0], pb1 = *(const float4*)&stT[lvb][k0+4];
            vA -= DOT4(a.lo, pa0) + DOT4(a.hi, pa1);
            vB -= DOT4(a.lo, pb0) + DOT4(a.hi, pb1);
        }
        vnw[w][lane][0] = vA;
        vnw[w][lane][1] = vB;

        // state update: s = a_dec*s + sum_r vn[r]*kd[r][c2..c2+1]  (wave-local)
        const float a_dec = EGw[cid];
        sA.x *= a_dec; sA.y *= a_dec; sB.x *= a_dec; sB.y *= a_dec;
        for (int r = 0; r < 64; ++r) {
            float2 vv = *(const float2*)&vnw[w][r];           // broadcast
            float2 kv = *(const float2*)&kd[cur][r][c2];
            sA.x += vv.x*kv.x; sA.y += vv.x*kv.y;
            sB.x += vv.y*kv.x; sB.y += vv.y*kv.y;
        }
        // mirror new state to LDS for next chunk's vn reads (wave-private rows)
        *(float2*)&stT[lva][c2] = sA;
        *(float2*)&stT[lvb][c2] = sB;

        cur ^= 1;
    }
}

// ---------------- Phase 3: outputs (4096 blocks = chunk x Dv-half) ----------------
// (unchanged)
__global__ __launch_bounds__(256) void dr_phase3(
    const float* __restrict__ Q,
    const unsigned short* __restrict__ Uw, const unsigned short* __restrict__ KCDw,
    const unsigned short* __restrict__ ATTNw, const unsigned short* __restrict__ STw,
    const float* __restrict__ RQw, float* __restrict__ Out)
{
    __shared__ __align__(16) __half         qh[64][136];  // q*rq*exp(gcs) (f16, swz)
    __shared__ __align__(16) unsigned short kch[64][136]; // kcd bf16 raw (swz)
    __shared__ __align__(16) unsigned short sth[64][136]; // state^T bf16 raw (swz)
    __shared__ __align__(16) unsigned short ath[64][72];  // attn bf16 raw (swz)
    __shared__ float vnT[64][68];                         // v_new^T f32 (swz)

    const int tid = threadIdx.x;
    const int half = blockIdx.x & 1;
    const int cid = blockIdx.x >> 1;
    const int n = cid & (NC_-1), bh = cid >> 6;
    const int h = bh & (H_-1), b = bh >> 4;
    const int rowbase = (b*S_ + n*CK_)*H_ + h;
    const int vbase = half*64;

    #pragma unroll
    for (int i = 0; i < 8; ++i) {
        int idx4 = tid + 256*i;
        int r = idx4 >> 5, c0 = (idx4 & 31)*4;
        float rq = RQw[cid*64 + r];
        float4 qv = *(const float4*)(Q + (size_t)(rowbase + r*H_)*DK_ + c0);
        qv.x *= rq; qv.y *= rq; qv.z *= rq; qv.w *= rq;
        f4toh4(&qh[r][SWH(c0, r)], qv);
        uint2 kcv = ((const uint2*)(KCDw + (size_t)cid*8192))[idx4];
        *(uint2*)&kch[r][SWH(c0, r)] = kcv;
        uint2 stv = ((const uint2*)(STw + ((size_t)cid*128 + vbase)*128))[idx4];
        *(uint2*)&sth[r][SWH(c0, r)] = stv;
    }
    #pragma unroll
    for (int i = 0; i < 4; ++i) {
        int idx4 = tid + 256*i;
        int r = idx4 >> 4, j0 = (idx4 & 15)*4;
        uint2 av = ((const uint2*)(ATTNw + (size_t)cid*4096))[idx4];
        *(uint2*)&ath[r][SWH(j0, r)] = av;
    }
    __syncthreads();

    const int r0 = (tid >> 4)*4, v4 = (tid & 15)*4;

    // vn = u - kc @ state  -> vnT[v][r] (f32, swizzled)
    {
        float4 acc[4];   // acc[x].{x,y,z,w} = vn[r0+x][v4+0..3]
        #pragma unroll
        for (int x = 0; x < 4; ++x) {
            ushort4 uv = *(const ushort4*)(Uw + (size_t)cid*8192 + (r0+x)*128 + vbase + v4);
            acc[x].x = bf2f(uv.x); acc[x].y = bf2f(uv.y); acc[x].z = bf2f(uv.z); acc[x].w = bf2f(uv.w);
        }
        for (int k0 = 0; k0 < 128; k0 += 8) {
            f8 A[4], Bv[4];
            #pragma unroll
            for (int x = 0; x < 4; ++x) A[x]  = unp_bf16x8(*(const uint4*)&kch[r0+x][SWH(k0, r0+x)]);
            #pragma unroll
            for (int y = 0; y < 4; ++y) Bv[y] = unp_bf16x8(*(const uint4*)&sth[v4+y][SWH(k0, v4+y)]);
            #pragma unroll
            for (int x = 0; x < 4; ++x) {
                acc[x].x -= DOT4(A[x].lo, Bv[0].lo) + DOT4(A[x].hi, Bv[0].hi);
                acc[x].y -= DOT4(A[x].lo, Bv[1].lo) + DOT4(A[x].hi, Bv[1].hi);
                acc[x].z -= DOT4(A[x].lo, Bv[2].lo) + DOT4(A[x].hi, Bv[2].hi);
                acc[x].w -= DOT4(A[x].lo, Bv[3].lo) + DOT4(A[x].hi, Bv[3].hi);
            }
        }
        #pragma unroll
        for (int x = 0; x < 4; ++x) {
            vnT[v4+0][SWV(r0+x, v4+0)] = acc[x].x;
            vnT[v4+1][SWV(r0+x, v4+1)] = acc[x].y;
            vnT[v4+2][SWV(r0+x, v4+2)] = acc[x].z;
            vnT[v4+3][SWV(r0+x, v4+3)] = acc[x].w;
        }
    }
    __syncthreads();

    // o = qg @ state + attn @ vn
    {
        float4 acc[4] = {};   // acc[x].{y} = o[r0+x][vbase+v4+y]
        for (int k0 = 0; k0 < 128; k0 += 8) {
            f8 A[4], Bv[4];
            #pragma unroll
            for (int x = 0; x < 4; ++x) A[x]  = unp_f16x8(*(const uint4*)&qh[r0+x][SWH(k0, r0+x)]);
            #pragma unroll
            for (int y = 0; y < 4; ++y) Bv[y] = unp_bf16x8(*(const uint4*)&sth[v4+y][SWH(k0, v4+y)]);
            #pragma unroll
            for (int x = 0; x < 4; ++x) {
                acc[x].x += DOT4(A[x].lo, Bv[0].lo) + DOT4(A[x].hi, Bv[0].hi);
                acc[x].y += DOT4(A[x].lo, Bv[1].lo) + DOT4(A[x].hi, Bv[1].hi);
                acc[x].z += DOT4(A[x].lo, Bv[2].lo) + DOT4(A[x].hi, Bv[2].hi);
                acc[x].w += DOT4(A[x].lo, Bv[3].lo) + DOT4(A[x].hi, Bv[3].hi);
            }
        }
        for (int j0 = 0; j0 <= r0+3; j0 += 8) {
            f8 A[4];
            #pragma unroll
            for (int x = 0; x < 4; ++x) A[x] = unp_bf16x8(*(const uint4*)&ath[r0+x][SWH(j0, r0+x)]);
            float4 bLo[4], bHi[4];
            #pragma unroll
            for (int y = 0; y < 4; ++y) {
                bLo[y] = *(const float4*)&vnT[v4+y][SWV(j0,   v4+y)];
                bHi[y] = *(const float4*)&vnT[v4+y][SWV(j0+4, v4+y)];
            }
            #pragma unroll
            for (int x = 0; x < 4; ++x) {
                acc[x].x += DOT4(A[x].lo, bLo[0]) + DOT4(A[x].hi, bHi[0]);
                acc[x].y += DOT4(A[x].lo, bLo[1]) + DOT4(A[x].hi, bHi[1]);
                acc[x].z += DOT4(A[x].lo, bLo[2]) + DOT4(A[x].hi, bHi[2]);
                acc[x].w += DOT4(A[x].lo, bLo[3]) + DOT4(A[x].hi, bHi[3]);
            }
        }
        #pragma unroll
        for (int x = 0; x < 4; ++x)
            *(float4*)(Out + (size_t)(rowbase + (r0+x)*H_)*DV_ + vbase + v4) = acc[x];
    }
}

extern "C" void kernel_launch(void* const* d_in, const int* in_sizes, int n_in,
                              void* d_out, int out_size, void* d_ws, size_t ws_size,
                              hipStream_t stream) {
    (void)in_sizes; (void)n_in; (void)out_size; (void)ws_size;
    const float* Q  = (const float*)d_in[0];
    const float* K  = (const float*)d_in[1];
    const float* V  = (const float*)d_in[2];
    const float* G  = (const float*)d_in[3];
    const float* Bt = (const float*)d_in[4];
    float* Out = (float*)d_out;

    // ws layout: U bf16 | KCD bf16 | ATTN bf16 | ST bf16 | RQ f32 | RK f32 | EG f32
    unsigned short* Uw    = (unsigned short*)d_ws;
    unsigned short* KCDw  = Uw    + (size_t)2048*64*128;
    unsigned short* ATTNw = KCDw  + (size_t)2048*64*128;
    unsigned short* STw   = ATTNw + (size_t)2048*64*64;
    float* RQw = (float*)(STw + (size_t)2048*128*128);
    float* RKw = RQw + 2048*64;
    float* EGw = RKw + 2048*64;

    dr_phase1<<<2048, 256, 0, stream>>>(Q, K, V, G, Bt, Uw, KCDw, ATTNw, RQw, RKw, EGw);
    dr_phase2<<<256, 512, 0, stream>>>(K, Uw, KCDw, RKw, EGw, STw);
    dr_phase3<<<4096, 256, 0, stream>>>(Q, Uw, KCDw, ATTNw, STw, RQw, Out);
}

// Round 5
// 806.174 us; speedup vs baseline: 1.1588x; 1.0087x over previous
//
#include <hip/hip_runtime.h>
#include <hip/hip_fp16.h>

#define B_   2
#define S_   4096
#define H_   16
#define DK_  128
#define DV_  128
#define CK_  64
#define NC_  (S_/CK_)            // 64 chunks per sequence
#define QSCALE 0.08838834764831845f   // 128^-0.5

#define DOT4(a,b) ((a).x*(b).x + (a).y*(b).y + (a).z*(b).z + (a).w*(b).w)

// 16B-granule XOR swizzles: kill 8-way bank conflicts on multi-row reads.
#define SWH(c, r) (((((c) >> 3) ^ (((r) >> 2) & 7)) << 3) | ((c) & 7))
#define SWV(c, r) (((((c) >> 2) ^ (((r) >> 2) & 7)) << 2) | ((c) & 3))

static __device__ __forceinline__ unsigned short f2bf(float x) {
    unsigned u = __float_as_uint(x);
    unsigned r = u + 0x7fffu + ((u >> 16) & 1u);
    return (unsigned short)(r >> 16);
}
static __device__ __forceinline__ float bf2f(unsigned short h) {
    return __uint_as_float(((unsigned)h) << 16);
}
static __device__ __forceinline__ float4 h4tof4(const __half* p) {
    float2 f01 = __half22float2(*(const __half2*)p);
    float2 f23 = __half22float2(*(const __half2*)(p + 2));
    return make_float4(f01.x, f01.y, f23.x, f23.y);
}
static __device__ __forceinline__ void f4toh4(__half* p, float4 v) {
    *(__half2*)p       = __floats2half2_rn(v.x, v.y);
    *(__half2*)(p + 2) = __floats2half2_rn(v.z, v.w);
}

struct f8 { float4 lo, hi; };
static __device__ __forceinline__ f8 unp_bf16x8(uint4 u) {
    f8 r;
    r.lo.x = __uint_as_float(u.x << 16); r.lo.y = __uint_as_float(u.x & 0xffff0000u);
    r.lo.z = __uint_as_float(u.y << 16); r.lo.w = __uint_as_float(u.y & 0xffff0000u);
    r.hi.x = __uint_as_float(u.z << 16); r.hi.y = __uint_as_float(u.z & 0xffff0000u);
    r.hi.z = __uint_as_float(u.w << 16); r.hi.w = __uint_as_float(u.w & 0xffff0000u);
    return r;
}
static __device__ __forceinline__ f8 unp_f16x8(uint4 u) {
    f8 r;
    float2 a = __half22float2(*(__half2*)&u.x), b = __half22float2(*(__half2*)&u.y);
    float2 c = __half22float2(*(__half2*)&u.z), d = __half22float2(*(__half2*)&u.w);
    r.lo = make_float4(a.x, a.y, b.x, b.y);
    r.hi = make_float4(c.x, c.y, d.x, d.y);
    return r;
}

// ---------------- Phase 1: per-chunk (parallel over 2048 chunks) ----------------
// (unchanged)
__global__ __launch_bounds__(256) void dr_phase1(
    const float* __restrict__ Q, const float* __restrict__ K,
    const float* __restrict__ V, const float* __restrict__ G,
    const float* __restrict__ Bt,
    unsigned short* __restrict__ Uw, unsigned short* __restrict__ KCDw,
    unsigned short* __restrict__ ATTNw,
    float* __restrict__ RQw, float* __restrict__ RKw, float* __restrict__ EGw)
{
    __shared__ float kn[64][132];                 // raw k, swizzled
    __shared__ __align__(16) __half bufh[64][136]; // v*beta, then raw q (f16)
    __shared__ float T[64][68];
    __shared__ float tmp[32][36];                 // blocked-inverse scratch
    __shared__ float bet[64], rn[64], epos[64], eneg[64], cL[64], cR[64];

    const int tid = threadIdx.x;
    const int cid = blockIdx.x;
    const int n   = cid & (NC_ - 1);
    const int bh  = cid >> 6;
    const int h   = bh & (H_ - 1);
    const int b   = bh >> 4;
    const int rowbase = (b*S_ + n*CK_)*H_ + h;

    // A: stage raw K (swizzled); wave0: shfl-scan of g, exps, beta
    #pragma unroll
    for (int i = 0; i < 8; ++i) {
        int idx4 = tid + 256*i;
        int r = idx4 >> 5, c0 = (idx4 & 31) << 2;
        *(float4*)&kn[r][c0 ^ (r & 28)] =
            *(const float4*)(K + (size_t)(rowbase + r*H_)*DK_ + c0);
    }
    if (tid < 64) {
        float g = G[rowbase + tid*H_];
        #pragma unroll
        for (int off = 1; off < 64; off <<= 1) {
            float o = __shfl_up(g, off, 64);
            if (tid >= off) g += o;
        }
        float ep = expf(g);
        epos[tid] = ep;
        eneg[tid] = expf(-g);
        bet[tid]  = Bt[rowbase + tid*H_];
        if (tid == 63) EGw[cid] = ep;
    }
    __syncthreads();

    // B: stage v*beta -> f16; k row norms -> rn, cL, cR, RK
    #pragma unroll
    for (int i = 0; i < 8; ++i) {
        int idx4 = tid + 256*i;
        int r = idx4 >> 5, c0 = (idx4 & 31) << 2;
        float bb = bet[r];
        float4 vv = *(const float4*)(V + (size_t)(rowbase + r*H_)*DV_ + c0);
        vv.x *= bb; vv.y *= bb; vv.z *= bb; vv.w *= bb;
        f4toh4(&bufh[r][c0], vv);
    }
    if (tid < 64) {
        const int xr = tid & 28;
        float s = 0.f;
        #pragma unroll
        for (int c = 0; c < 128; c += 4) { float4 x = *(float4*)&kn[tid][c ^ xr]; s += DOT4(x,x); }
        float r_ = rsqrtf(s + 1e-6f);
        rn[tid] = r_;
        RKw[cid*64 + tid] = r_*epos[63]*eneg[tid];
        cL[tid] = bet[tid]*epos[tid]*r_;
        cR[tid] = eneg[tid]*r_;
    }
    __syncthreads();

    // C: T = -strict_lower( cL(i)*cR(j) * (kraw_i . kraw_j) )
    {
        const int i0 = (tid >> 4) << 2, j0 = (tid & 15) << 2;
        const int xi = i0 & 28, xj = j0 & 28;
        float acc[4][4] = {};
        if (j0 <= i0) {
            for (int c = 0; c < 128; c += 4) {
                float4 a0 = *(float4*)&kn[i0  ][c ^ xi], a1 = *(float4*)&kn[i0+1][c ^ xi];
                float4 a2 = *(float4*)&kn[i0+2][c ^ xi], a3 = *(float4*)&kn[i0+3][c ^ xi];
                float4 b0 = *(float4*)&kn[j0  ][c ^ xj], b1 = *(float4*)&kn[j0+1][c ^ xj];
                float4 b2 = *(float4*)&kn[j0+2][c ^ xj], b3 = *(float4*)&kn[j0+3][c ^ xj];
                acc[0][0]+=DOT4(a0,b0); acc[0][1]+=DOT4(a0,b1); acc[0][2]+=DOT4(a0,b2); acc[0][3]+=DOT4(a0,b3);
                acc[1][0]+=DOT4(a1,b0); acc[1][1]+=DOT4(a1,b1); acc[1][2]+=DOT4(a1,b2); acc[1][3]+=DOT4(a1,b3);
                acc[2][0]+=DOT4(a2,b0); acc[2][1]+=DOT4(a2,b1); acc[2][2]+=DOT4(a2,b2); acc[2][3]+=DOT4(a2,b3);
                acc[3][0]+=DOT4(a3,b0); acc[3][1]+=DOT4(a3,b1); acc[3][2]+=DOT4(a3,b2); acc[3][3]+=DOT4(a3,b3);
            }
        }
        #pragma unroll
        for (int x = 0; x < 4; ++x) {
            float fi = cL[i0+x];
            #pragma unroll
            for (int y = 0; y < 4; ++y) {
                int i = i0+x, j = j0+y;
                T[i][j] = (i > j) ? (-fi*cR[j]*acc[x][y]) : 0.f;
            }
        }
    }
    __syncthreads();

    // D1: copy diagonal 16x16 blocks (original -A) into tmp
    {
        float* tf = &tmp[0][0];
        for (int t = tid; t < 1024; t += 256) {
            int d = t >> 8, i = (t >> 4) & 15, j = t & 15;
            tf[t] = T[(d<<4) + i][(d<<4) + j];
        }
    }
    __syncthreads();
    // D2: invert each diagonal block in place, one thread per (block, column)
    if (tid < 64) {
        const float* Ad = &tmp[0][0] + ((tid >> 4) << 8);
        const int j = tid & 15, R = (tid >> 4) << 4;
        for (int i = j+1; i < 16; ++i) {
            float x = Ad[(i<<4) + j];
            for (int l = j+1; l < i; ++l) x += Ad[(i<<4) + l] * T[R+l][R+j];
            T[R+i][R+j] = x;
        }
    }
    __syncthreads();
    // D3: 16 -> 32 (two pairs). X21 = (I+X22) * T21 * (I+X11)
    {
        const int p = tid >> 7, rem = tid & 127, i = rem >> 3, j0 = (rem & 7) << 1;
        const int bb2 = p << 5;
        float x0 = T[bb2+16+i][bb2+j0], x1 = T[bb2+16+i][bb2+j0+1];
        for (int l = j0+1; l < 16; ++l) {
            float a = T[bb2+16+i][bb2+l];
            x0 += a * T[bb2+l][bb2+j0];
            if (l > j0+1) x1 += a * T[bb2+l][bb2+j0+1];
        }
        tmp[(p<<4)+i][j0] = x0; tmp[(p<<4)+i][j0+1] = x1;
        __syncthreads();
        float y0 = tmp[(p<<4)+i][j0], y1 = tmp[(p<<4)+i][j0+1];
        for (int l = 0; l < i; ++l) {
            float a = T[bb2+16+i][bb2+16+l];
            y0 += a * tmp[(p<<4)+l][j0];
            y1 += a * tmp[(p<<4)+l][j0+1];
        }
        T[bb2+16+i][bb2+j0] = y0; T[bb2+16+i][bb2+j0+1] = y1;
    }
    __syncthreads();
    // D4: 32 -> 64
    {
        const int i = tid >> 3, j0 = (tid & 7) << 2;
        float x0 = T[32+i][j0], x1 = T[32+i][j0+1], x2 = T[32+i][j0+2], x3 = T[32+i][j0+3];
        for (int l = j0+1; l < 32; ++l) {
            float a = T[32+i][l];
            x0 += a * T[l][j0];
            if (l > j0+1) x1 += a * T[l][j0+1];
            if (l > j0+2) x2 += a * T[l][j0+2];
            if (l > j0+3) x3 += a * T[l][j0+3];
        }
        tmp[i][j0] = x0; tmp[i][j0+1] = x1; tmp[i][j0+2] = x2; tmp[i][j0+3] = x3;
        __syncthreads();
        float y0 = tmp[i][j0], y1 = tmp[i][j0+1], y2 = tmp[i][j0+2], y3 = tmp[i][j0+3];
        for (int l = 0; l < i; ++l) {
            float a = T[32+i][32+l];
            y0 += a * tmp[l][j0];   y1 += a * tmp[l][j0+1];
            y2 += a * tmp[l][j0+2]; y3 += a * tmp[l][j0+3];
        }
        T[32+i][j0] = y0; T[32+i][j0+1] = y1; T[32+i][j0+2] = y2; T[32+i][j0+3] = y3;
    }
    __syncthreads();

    // E: U = (I+T) @ (v*beta),  KCD = (I+T) @ (k*beta*exp(gcs))  -> bf16
    {
        unsigned short* Up = Uw + (size_t)cid*(CK_*DV_);
        for (int tt = tid; tt < 512; tt += 256) {
            const int i0 = (tt >> 5) << 2, c0 = (tt & 31) << 2;
            float4 acc[4];
            #pragma unroll
            for (int x = 0; x < 4; ++x) acc[x] = h4tof4(&bufh[i0+x][c0]);
            for (int j0 = 0; j0 <= i0; j0 += 4) {
                float4 t0 = *(float4*)&T[i0][j0],   t1 = *(float4*)&T[i0+1][j0];
                float4 t2 = *(float4*)&T[i0+2][j0], t3 = *(float4*)&T[i0+3][j0];
                float4 b0 = h4tof4(&bufh[j0][c0]),   b1 = h4tof4(&bufh[j0+1][c0]);
                float4 b2 = h4tof4(&bufh[j0+2][c0]), b3 = h4tof4(&bufh[j0+3][c0]);
                acc[0].x += t0.x*b0.x + t0.y*b1.x + t0.z*b2.x + t0.w*b3.x;
                acc[0].y += t0.x*b0.y + t0.y*b1.y + t0.z*b2.y + t0.w*b3.y;
                acc[0].z += t0.x*b0.z + t0.y*b1.z + t0.z*b2.z + t0.w*b3.z;
                acc[0].w += t0.x*b0.w + t0.y*b1.w + t0.z*b2.w + t0.w*b3.w;
                acc[1].x += t1.x*b0.x + t1.y*b1.x + t1.z*b2.x + t1.w*b3.x;
                acc[1].y += t1.x*b0.y + t1.y*b1.y + t1.z*b2.y + t1.w*b3.y;
                acc[1].z += t1.x*b0.z + t1.y*b1.z + t1.z*b2.z + t1.w*b3.z;
                acc[1].w += t1.x*b0.w + t1.y*b1.w + t1.z*b2.w + t1.w*b3.w;
                acc[2].x += t2.x*b0.x + t2.y*b1.x + t2.z*b2.x + t2.w*b3.x;
                acc[2].y += t2.x*b0.y + t2.y*b1.y + t2.z*b2.y + t2.w*b3.y;
                acc[2].z += t2.x*b0.z + t2.y*b1.z + t2.z*b2.z + t2.w*b3.z;
                acc[2].w += t2.x*b0.w + t2.y*b1.w + t2.z*b2.w + t2.w*b3.w;
                acc[3].x += t3.x*b0.x + t3.y*b1.x + t3.z*b2.x + t3.w*b3.x;
                acc[3].y += t3.x*b0.y + t3.y*b1.y + t3.z*b2.y + t3.w*b3.y;
                acc[3].z += t3.x*b0.z + t3.y*b1.z + t3.z*b2.z + t3.w*b3.z;
                acc[3].w += t3.x*b0.w + t3.y*b1.w + t3.z*b2.w + t3.w*b3.w;
            }
            #pragma unroll
            for (int x = 0; x < 4; ++x) {
                ushort4 o; o.x = f2bf(acc[x].x); o.y = f2bf(acc[x].y);
                o.z = f2bf(acc[x].z); o.w = f2bf(acc[x].w);
                *(ushort4*)(Up + (i0+x)*DV_ + c0) = o;
            }
        }
        unsigned short* Kp = KCDw + (size_t)cid*(CK_*DK_);
        for (int tt = tid; tt < 512; tt += 256) {
            const int i0 = (tt >> 5) << 2, c0 = (tt & 31) << 2;
            const int xi = i0 & 28;
            float4 acc[4];
            #pragma unroll
            for (int x = 0; x < 4; ++x) {
                float wi = cL[i0+x];
                float4 kv = *(float4*)&kn[i0+x][c0 ^ xi];
                acc[x].x = kv.x*wi; acc[x].y = kv.y*wi; acc[x].z = kv.z*wi; acc[x].w = kv.w*wi;
            }
            for (int j0 = 0; j0 <= i0; j0 += 4) {
                const int xj = j0 & 28;
                float w0 = cL[j0], w1 = cL[j0+1], w2 = cL[j0+2], w3 = cL[j0+3];
                float4 t0 = *(float4*)&T[i0][j0],   t1 = *(float4*)&T[i0+1][j0];
                float4 t2 = *(float4*)&T[i0+2][j0], t3 = *(float4*)&T[i0+3][j0];
                float4 b0 = *(float4*)&kn[j0  ][c0 ^ xj], b1 = *(float4*)&kn[j0+1][c0 ^ xj];
                float4 b2 = *(float4*)&kn[j0+2][c0 ^ xj], b3 = *(float4*)&kn[j0+3][c0 ^ xj];
                b0.x*=w0; b0.y*=w0; b0.z*=w0; b0.w*=w0;
                b1.x*=w1; b1.y*=w1; b1.z*=w1; b1.w*=w1;
                b2.x*=w2; b2.y*=w2; b2.z*=w2; b2.w*=w2;
                b3.x*=w3; b3.y*=w3; b3.z*=w3; b3.w*=w3;
                acc[0].x += t0.x*b0.x + t0.y*b1.x + t0.z*b2.x + t0.w*b3.x;
                acc[0].y += t0.x*b0.y + t0.y*b1.y + t0.z*b2.y + t0.w*b3.y;
                acc[0].z += t0.x*b0.z + t0.y*b1.z + t0.z*b2.z + t0.w*b3.z;
                acc[0].w += t0.x*b0.w + t0.y*b1.w + t0.z*b2.w + t0.w*b3.w;
                acc[1].x += t1.x*b0.x + t1.y*b1.x + t1.z*b2.x + t1.w*b3.x;
                acc[1].y += t1.x*b0.y + t1.y*b1.y + t1.z*b2.y + t1.w*b3.y;
                acc[1].z += t1.x*b0.z + t1.y*b1.z + t1.z*b2.z + t1.w*b3.z;
                acc[1].w += t1.x*b0.w + t1.y*b1.w + t1.z*b2.w + t1.w*b3.w;
                acc[2].x += t2.x*b0.x + t2.y*b1.x + t2.z*b2.x + t2.w*b3.x;
                acc[2].y += t2.x*b0.y + t2.y*b1.y + t2.z*b2.y + t2.w*b3.y;
                acc[2].z += t2.x*b0.z + t2.y*b1.z + t2.z*b2.z + t2.w*b3.z;
                acc[2].w += t2.x*b0.w + t2.y*b1.w + t2.z*b2.w + t2.w*b3.w;
                acc[3].x += t3.x*b0.x + t3.y*b1.x + t3.z*b2.x + t3.w*b3.x;
                acc[3].y += t3.x*b0.y + t3.y*b1.y + t3.z*b2.y + t3.w*b3.y;
                acc[3].z += t3.x*b0.z + t3.y*b1.z + t3.z*b2.z + t3.w*b3.z;
                acc[3].w += t3.x*b0.w + t3.y*b1.w + t3.z*b2.w + t3.w*b3.w;
            }
            #pragma unroll
            for (int x = 0; x < 4; ++x) {
                ushort4 o; o.x = f2bf(acc[x].x); o.y = f2bf(acc[x].y);
                o.z = f2bf(acc[x].z); o.w = f2bf(acc[x].w);
                *(ushort4*)(Kp + (i0+x)*DK_ + c0) = o;
            }
        }
    }
    __syncthreads();

    // F: stage raw q -> f16 (scale folded into epilogue)
    #pragma unroll
    for (int i = 0; i < 8; ++i) {
        int idx4 = tid + 256*i;
        int r = idx4 >> 5, c0 = (idx4 & 31) << 2;
        f4toh4(&bufh[r][c0], *(const float4*)(Q + (size_t)(rowbase + r*H_)*DK_ + c0));
    }
    __syncthreads();
    // G: q row norms (QSCALE folded); RQ
    if (tid < 64) {
        float s = 0.f;
        #pragma unroll
        for (int c = 0; c < 128; c += 4) { float4 x = h4tof4(&bufh[tid][c]); s += DOT4(x,x); }
        float r_ = rsqrtf(s + 1e-6f)*QSCALE;
        rn[tid] = r_;
        RQw[cid*64 + tid] = r_*epos[tid];
    }
    __syncthreads();

    // H: attn = tril(q@k^T * decay) -> bf16
    {
        unsigned short* Ap = ATTNw + (size_t)cid*(CK_*CK_);
        const int i0 = (tid >> 4) << 2, j0 = (tid & 15) << 2;
        const int xj = j0 & 28;
        float acc[4][4] = {};
        if (j0 <= i0) {
            for (int c = 0; c < 128; c += 4) {
                float4 a0 = h4tof4(&bufh[i0  ][c]), a1 = h4tof4(&bufh[i0+1][c]);
                float4 a2 = h4tof4(&bufh[i0+2][c]), a3 = h4tof4(&bufh[i0+3][c]);
                float4 b0 = *(float4*)&kn[j0  ][c ^ xj], b1 = *(float4*)&kn[j0+1][c ^ xj];
                float4 b2 = *(float4*)&kn[j0+2][c ^ xj], b3 = *(float4*)&kn[j0+3][c ^ xj];
                acc[0][0]+=DOT4(a0,b0); acc[0][1]+=DOT4(a0,b1); acc[0][2]+=DOT4(a0,b2); acc[0][3]+=DOT4(a0,b3);
                acc[1][0]+=DOT4(a1,b0); acc[1][1]+=DOT4(a1,b1); acc[1][2]+=DOT4(a1,b2); acc[1][3]+=DOT4(a1,b3);
                acc[2][0]+=DOT4(a2,b0); acc[2][1]+=DOT4(a2,b1); acc[2][2]+=DOT4(a2,b2); acc[2][3]+=DOT4(a2,b3);
                acc[3][0]+=DOT4(a3,b0); acc[3][1]+=DOT4(a3,b1); acc[3][2]+=DOT4(a3,b2); acc[3][3]+=DOT4(a3,b3);
            }
        }
        #pragma unroll
        for (int x = 0; x < 4; ++x) {
            ushort4 o;
            int i = i0+x;
            float fi = rn[i]*epos[i];
            float v0 = (j0   <= i) ? acc[x][0]*fi*cR[j0]   : 0.f;
            float v1 = (j0+1 <= i) ? acc[x][1]*fi*cR[j0+1] : 0.f;
            float v2 = (j0+2 <= i) ? acc[x][2]*fi*cR[j0+2] : 0.f;
            float v3 = (j0+3 <= i) ? acc[x][3]*fi*cR[j0+3] : 0.f;
            o.x = f2bf(v0); o.y = f2bf(v1); o.z = f2bf(v2); o.w = f2bf(v3);
            *(ushort4*)(Ap + i*CK_ + j0) = o;
        }
    }
}

// ---------------- Phase 2: state recurrence (256 blocks = bh x 8 v-slices of 16) --------
// Round-3 structure + XCD-affinity remap: bid ≡ bh (mod 8) so all 8 v-slice blocks of a
// bh share one XCD -> K/KCD/U chunk streams fetched once per XCD, L2 serves the rest.
// Kills the 3.6x HBM over-fetch (460MB -> ~140MB) and the prefetch-latency stall.
#define P2_LOAD(nn) do { \
    const int cid_ = bh*NC_ + (nn); \
    const int rb_ = (b*S_ + (nn)*CK_)*H_ + h; \
    _Pragma("unroll") \
    for (int i = 0; i < 4; ++i) { \
        int idx4 = tid + 512*i; \
        int r = idx4 >> 5; \
        pk[i]  = *(const float4*)(K + (size_t)(rb_ + r*H_)*DK_ + ((idx4 & 31)*4)); \
        pc[i]  = ((const uint2*)(KCDw + (size_t)cid_*8192))[idx4]; \
        prk[i] = RKw[cid_*64 + r]; \
    } \
    pu = *(const unsigned*)(Uw + (size_t)cid_*8192 + lane*128 + v0 + 2*w); \
} while(0)

__global__ __launch_bounds__(512) void dr_phase2(
    const float* __restrict__ K,
    const unsigned short* __restrict__ Uw, const unsigned short* __restrict__ KCDw,
    const float* __restrict__ RKw, const float* __restrict__ EGw,
    unsigned short* __restrict__ STw)
{
    __shared__ __align__(16) unsigned short kch[2][64][136]; // kcd raw bf16, SWH-swizzled
    __shared__ float kd[2][64][132];   // k_norm * exp(g_last - gcs), f32
    __shared__ float stT[16][132];     // state^T slice (row v owned by wave v>>1)
    __shared__ float vnw[8][64][2];    // per-wave vn columns (write by lane, read bcast)

    const int tid = threadIdx.x;
    // XCD-affinity decode: xcd = bid&7 == bh&7; 4 bh per XCD x 8 v-slices = 32 blocks/XCD.
    const int bidx = blockIdx.x;
    const int xcd  = bidx & 7;
    const int slot = bidx >> 3;            // 0..31
    const int vs   = slot >> 2;            // 0..7
    const int bh   = ((slot & 3) << 3) | xcd;   // 0..31, bh%8 == xcd
    const int h = bh & (H_-1), b = bh >> 4;
    const int v0 = vs*16;
    const int w = tid >> 6, lane = tid & 63;
    const int lva = 2*w, lvb = 2*w + 1;          // this wave's state rows (local)
    const int c2 = 2*lane;                        // this lane's state col pair

    // init: state regs + LDS mirror (wave-private, no barrier needed)
    float2 sA = {0.f, 0.f}, sB = {0.f, 0.f};
    *(float2*)&stT[lva][c2] = sA;
    *(float2*)&stT[lvb][c2] = sB;

    float4 pk[4]; uint2 pc[4]; float prk[4]; unsigned pu;
    P2_LOAD(0);

    int cur = 0;
    for (int n = 0; n < NC_; ++n) {
        const int cid = bh*NC_ + n;
        const float u0 = bf2f((unsigned short)(pu & 0xffff));
        const float u1 = bf2f((unsigned short)(pu >> 16));

        // stage chunk n into buf[cur] (disjoint from buf[cur^1] others may still read)
        #pragma unroll
        for (int i = 0; i < 4; ++i) {
            int idx4 = tid + 512*i;
            int r = idx4 >> 5, c0 = (idx4 & 31)*4;
            *(uint2*)&kch[cur][r][SWH(c0, r)] = pc[i];
            float4 kv = pk[i];
            kv.x *= prk[i]; kv.y *= prk[i]; kv.z *= prk[i]; kv.w *= prk[i];
            *(float4*)&kd[cur][r][c0] = kv;
        }
        if (n+1 < NC_) P2_LOAD(n+1);     // issue next-chunk loads; land during compute
        __syncthreads();                  // buf[cur] ready for everyone

        // store pre-update state (entering chunk n) for phase 3, from regs
        {
            unsigned pA = (unsigned)f2bf(sA.x) | ((unsigned)f2bf(sA.y) << 16);
            unsigned pB = (unsigned)f2bf(sB.x) | ((unsigned)f2bf(sB.y) << 16);
            size_t base = ((size_t)cid*128 + v0)*128;
            *(unsigned*)(STw + base + (size_t)lva*128 + c2) = pA;
            *(unsigned*)(STw + base + (size_t)lvb*128 + c2) = pB;
        }

        // vn[lane][lva], vn[lane][lvb] = u - kc[lane,:] . stT[{lva,lvb},:]
        float vA = u0, vB = u1;
        for (int k0 = 0; k0 < 128; k0 += 8) {
            f8 a = unp_bf16x8(*(const uint4*)&kch[cur][lane][SWH(k0, lane)]);
            float4 pa0 = *(const float4*)&stT[lva][k0], pa1 = *(const float4*)&stT[lva][k0+4];
            float4 pb0 = *(const float4*)&stT[lvb][k0], pb1 = *(const float4*)&stT[lvb][k0+4];
            vA -= DOT4(a.lo, pa0) + DOT4(a.hi, pa1);
            vB -= DOT4(a.lo, pb0) + DOT4(a.hi, pb1);
        }
        vnw[w][lane][0] = vA;
        vnw[w][lane][1] = vB;

        // state update: s = a_dec*s + sum_r vn[r]*kd[r][c2..c2+1]  (wave-local)
        const float a_dec = EGw[cid];
        sA.x *= a_dec; sA.y *= a_dec; sB.x *= a_dec; sB.y *= a_dec;
        for (int r = 0; r < 64; ++r) {
            float2 vv = *(const float2*)&vnw[w][r];           // broadcast
            float2 kv = *(const float2*)&kd[cur][r][c2];
            sA.x += vv.x*kv.x; sA.y += vv.x*kv.y;
            sB.x += vv.y*kv.x; sB.y += vv.y*kv.y;
        }
        // mirror new state to LDS for next chunk's vn reads (wave-private rows)
        *(float2*)&stT[lva][c2] = sA;
        *(float2*)&stT[lvb][c2] = sB;

        cur ^= 1;
    }
}

// ---------------- Phase 3: outputs (4096 blocks = chunk x Dv-half) ----------------
// XCD-affinity remap: the two Dv-half blocks of one cid share an XCD (bid ≡ cid mod 8)
// so Q/KCD/ATTN are fetched once per pair instead of twice.
__global__ __launch_bounds__(256) void dr_phase3(
    const float* __restrict__ Q,
    const unsigned short* __restrict__ Uw, const unsigned short* __restrict__ KCDw,
    const unsigned short* __restrict__ ATTNw, const unsigned short* __restrict__ STw,
    const float* __restrict__ RQw, float* __restrict__ Out)
{
    __shared__ __align__(16) __half         qh[64][136];  // q*rq*exp(gcs) (f16, swz)
    __shared__ __align__(16) unsigned short kch[64][136]; // kcd bf16 raw (swz)
    __shared__ __align__(16) unsigned short sth[64][136]; // state^T bf16 raw (swz)
    __shared__ __align__(16) unsigned short ath[64][72];  // attn bf16 raw (swz)
    __shared__ float vnT[64][68];                         // v_new^T f32 (swz)

    const int tid = threadIdx.x;
    // XCD-affinity decode: cid%8 == bid%8; halves of a cid land on the same XCD.
    const int bidx = blockIdx.x;
    const int xcd  = bidx & 7;
    const int half = (bidx >> 3) & 1;
    const int cid  = ((bidx >> 4) << 3) | xcd;   // 0..2047
    const int n = cid & (NC_-1), bh = cid >> 6;
    const int h = bh & (H_-1), b = bh >> 4;
    const int rowbase = (b*S_ + n*CK_)*H_ + h;
    const int vbase = half*64;

    #pragma unroll
    for (int i = 0; i < 8; ++i) {
        int idx4 = tid + 256*i;
        int r = idx4 >> 5, c0 = (idx4 & 31)*4;
        float rq = RQw[cid*64 + r];
        float4 qv = *(const float4*)(Q + (size_t)(rowbase + r*H_)*DK_ + c0);
        qv.x *= rq; qv.y *= rq; qv.z *= rq; qv.w *= rq;
        f4toh4(&qh[r][SWH(c0, r)], qv);
        uint2 kcv = ((const uint2*)(KCDw + (size_t)cid*8192))[idx4];
        *(uint2*)&kch[r][SWH(c0, r)] = kcv;
        uint2 stv = ((const uint2*)(STw + ((size_t)cid*128 + vbase)*128))[idx4];
        *(uint2*)&sth[r][SWH(c0, r)] = stv;
    }
    #pragma unroll
    for (int i = 0; i < 4; ++i) {
        int idx4 = tid + 256*i;
        int r = idx4 >> 4, j0 = (idx4 & 15)*4;
        uint2 av = ((const uint2*)(ATTNw + (size_t)cid*4096))[idx4];
        *(uint2*)&ath[r][SWH(j0, r)] = av;
    }
    __syncthreads();

    const int r0 = (tid >> 4)*4, v4 = (tid & 15)*4;

    // vn = u - kc @ state  -> vnT[v][r] (f32, swizzled)
    {
        float4 acc[4];   // acc[x].{x,y,z,w} = vn[r0+x][v4+0..3]
        #pragma unroll
        for (int x = 0; x < 4; ++x) {
            ushort4 uv = *(const ushort4*)(Uw + (size_t)cid*8192 + (r0+x)*128 + vbase + v4);
            acc[x].x = bf2f(uv.x); acc[x].y = bf2f(uv.y); acc[x].z = bf2f(uv.z); acc[x].w = bf2f(uv.w);
        }
        for (int k0 = 0; k0 < 128; k0 += 8) {
            f8 A[4], Bv[4];
            #pragma unroll
            for (int x = 0; x < 4; ++x) A[x]  = unp_bf16x8(*(const uint4*)&kch[r0+x][SWH(k0, r0+x)]);
            #pragma unroll
            for (int y = 0; y < 4; ++y) Bv[y] = unp_bf16x8(*(const uint4*)&sth[v4+y][SWH(k0, v4+y)]);
            #pragma unroll
            for (int x = 0; x < 4; ++x) {
                acc[x].x -= DOT4(A[x].lo, Bv[0].lo) + DOT4(A[x].hi, Bv[0].hi);
                acc[x].y -= DOT4(A[x].lo, Bv[1].lo) + DOT4(A[x].hi, Bv[1].hi);
                acc[x].z -= DOT4(A[x].lo, Bv[2].lo) + DOT4(A[x].hi, Bv[2].hi);
                acc[x].w -= DOT4(A[x].lo, Bv[3].lo) + DOT4(A[x].hi, Bv[3].hi);
            }
        }
        #pragma unroll
        for (int x = 0; x < 4; ++x) {
            vnT[v4+0][SWV(r0+x, v4+0)] = acc[x].x;
            vnT[v4+1][SWV(r0+x, v4+1)] = acc[x].y;
            vnT[v4+2][SWV(r0+x, v4+2)] = acc[x].z;
            vnT[v4+3][SWV(r0+x, v4+3)] = acc[x].w;
        }
    }
    __syncthreads();

    // o = qg @ state + attn @ vn
    {
        float4 acc[4] = {};   // acc[x].{y} = o[r0+x][vbase+v4+y]
        for (int k0 = 0; k0 < 128; k0 += 8) {
            f8 A[4], Bv[4];
            #pragma unroll
            for (int x = 0; x < 4; ++x) A[x]  = unp_f16x8(*(const uint4*)&qh[r0+x][SWH(k0, r0+x)]);
            #pragma unroll
            for (int y = 0; y < 4; ++y) Bv[y] = unp_bf16x8(*(const uint4*)&sth[v4+y][SWH(k0, v4+y)]);
            #pragma unroll
            for (int x = 0; x < 4; ++x) {
                acc[x].x += DOT4(A[x].lo, Bv[0].lo) + DOT4(A[x].hi, Bv[0].hi);
                acc[x].y += DOT4(A[x].lo, Bv[1].lo) + DOT4(A[x].hi, Bv[1].hi);
                acc[x].z += DOT4(A[x].lo, Bv[2].lo) + DOT4(A[x].hi, Bv[2].hi);
                acc[x].w += DOT4(A[x].lo, Bv[3].lo) + DOT4(A[x].hi, Bv[3].hi);
            }
        }
        for (int j0 = 0; j0 <= r0+3; j0 += 8) {
            f8 A[4];
            #pragma unroll
            for (int x = 0; x < 4; ++x) A[x] = unp_bf16x8(*(const uint4*)&ath[r0+x][SWH(j0, r0+x)]);
            float4 bLo[4], bHi[4];
            #pragma unroll
            for (int y = 0; y < 4; ++y) {
                bLo[y] = *(const float4*)&vnT[v4+y][SWV(j0,   v4+y)];
                bHi[y] = *(const float4*)&vnT[v4+y][SWV(j0+4, v4+y)];
            }
            #pragma unroll
            for (int x = 0; x < 4; ++x) {
                acc[x].x += DOT4(A[x].lo, bLo[0]) + DOT4(A[x].hi, bHi[0]);
                acc[x].y += DOT4(A[x].lo, bLo[1]) + DOT4(A[x].hi, bHi[1]);
                acc[x].z += DOT4(A[x].lo, bLo[2]) + DOT4(A[x].hi, bHi[2]);
                acc[x].w += DOT4(A[x].lo, bLo[3]) + DOT4(A[x].hi, bHi[3]);
            }
        }
        #pragma unroll
        for (int x = 0; x < 4; ++x)
            *(float4*)(Out + (size_t)(rowbase + (r0+x)*H_)*DV_ + vbase + v4) = acc[x];
    }
}

extern "C" void kernel_launch(void* const* d_in, const int* in_sizes, int n_in,
                              void* d_out, int out_size, void* d_ws, size_t ws_size,
                              hipStream_t stream) {
    (void)in_sizes; (void)n_in; (void)out_size; (void)ws_size;
    const float* Q  = (const float*)d_in[0];
    const float* K  = (const float*)d_in[1];
    const float* V  = (const float*)d_in[2];
    const float* G  = (const float*)d_in[3];
    const float* Bt = (const float*)d_in[4];
    float* Out = (float*)d_out;

    // ws layout: U bf16 | KCD bf16 | ATTN bf16 | ST bf16 | RQ f32 | RK f32 | EG f32
    unsigned short* Uw    = (unsigned short*)d_ws;
    unsigned short* KCDw  = Uw    + (size_t)2048*64*128;
    unsigned short* ATTNw = KCDw  + (size_t)2048*64*128;
    unsigned short* STw   = ATTNw + (size_t)2048*64*64;
    float* RQw = (float*)(STw + (size_t)2048*128*128);
    float* RKw = RQw + 2048*64;
    float* EGw = RKw + 2048*64;

    dr_phase1<<<2048, 256, 0, stream>>>(Q, K, V, G, Bt, Uw, KCDw, ATTNw, RQw, RKw, EGw);
    dr_phase2<<<256, 512, 0, stream>>>(K, Uw, KCDw, RKw, EGw, STw);
    dr_phase3<<<4096, 256, 0, stream>>>(Q, Uw, KCDw, ATTNw, STw, RQw, Out);
}

// Round 6
// 668.886 us; speedup vs baseline: 1.3967x; 1.2052x over previous
//
#include <hip/hip_runtime.h>
#include <hip/hip_fp16.h>

#define B_   2
#define S_   4096
#define H_   16
#define DK_  128
#define DV_  128
#define CK_  64
#define NC_  (S_/CK_)            // 64 chunks per sequence
#define QSCALE 0.08838834764831845f   // 128^-0.5

#define DOT4(a,b) ((a).x*(b).x + (a).y*(b).y + (a).z*(b).z + (a).w*(b).w)

// 16B-granule XOR swizzles: kill 8-way bank conflicts on multi-row reads.
#define SWH(c, r) (((((c) >> 3) ^ (((r) >> 2) & 7)) << 3) | ((c) & 7))
#define SWV(c, r) (((((c) >> 2) ^ (((r) >> 2) & 7)) << 2) | ((c) & 3))

typedef __attribute__((ext_vector_type(8))) short bf16x8;
typedef __attribute__((ext_vector_type(4))) float f32x4;

static __device__ __forceinline__ unsigned short f2bf(float x) {
    unsigned u = __float_as_uint(x);
    unsigned r = u + 0x7fffu + ((u >> 16) & 1u);
    return (unsigned short)(r >> 16);
}
static __device__ __forceinline__ float bf2f(unsigned short h) {
    return __uint_as_float(((unsigned)h) << 16);
}
static __device__ __forceinline__ float4 h4tof4(const __half* p) {
    float2 f01 = __half22float2(*(const __half2*)p);
    float2 f23 = __half22float2(*(const __half2*)(p + 2));
    return make_float4(f01.x, f01.y, f23.x, f23.y);
}
static __device__ __forceinline__ void f4toh4(__half* p, float4 v) {
    *(__half2*)p       = __floats2half2_rn(v.x, v.y);
    *(__half2*)(p + 2) = __floats2half2_rn(v.z, v.w);
}

struct f8 { float4 lo, hi; };
static __device__ __forceinline__ f8 unp_bf16x8(uint4 u) {
    f8 r;
    r.lo.x = __uint_as_float(u.x << 16); r.lo.y = __uint_as_float(u.x & 0xffff0000u);
    r.lo.z = __uint_as_float(u.y << 16); r.lo.w = __uint_as_float(u.y & 0xffff0000u);
    r.hi.x = __uint_as_float(u.z << 16); r.hi.y = __uint_as_float(u.z & 0xffff0000u);
    r.hi.z = __uint_as_float(u.w << 16); r.hi.w = __uint_as_float(u.w & 0xffff0000u);
    return r;
}

// ---------------- Phase 1: per-chunk (parallel over 2048 chunks) ----------------
// (unchanged)
__global__ __launch_bounds__(256) void dr_phase1(
    const float* __restrict__ Q, const float* __restrict__ K,
    const float* __restrict__ V, const float* __restrict__ G,
    const float* __restrict__ Bt,
    unsigned short* __restrict__ Uw, unsigned short* __restrict__ KCDw,
    unsigned short* __restrict__ ATTNw,
    float* __restrict__ RQw, float* __restrict__ RKw, float* __restrict__ EGw)
{
    __shared__ float kn[64][132];                 // raw k, swizzled
    __shared__ __align__(16) __half bufh[64][136]; // v*beta, then raw q (f16)
    __shared__ float T[64][68];
    __shared__ float tmp[32][36];                 // blocked-inverse scratch
    __shared__ float bet[64], rn[64], epos[64], eneg[64], cL[64], cR[64];

    const int tid = threadIdx.x;
    const int cid = blockIdx.x;
    const int n   = cid & (NC_ - 1);
    const int bh  = cid >> 6;
    const int h   = bh & (H_ - 1);
    const int b   = bh >> 4;
    const int rowbase = (b*S_ + n*CK_)*H_ + h;

    // A: stage raw K (swizzled); wave0: shfl-scan of g, exps, beta
    #pragma unroll
    for (int i = 0; i < 8; ++i) {
        int idx4 = tid + 256*i;
        int r = idx4 >> 5, c0 = (idx4 & 31) << 2;
        *(float4*)&kn[r][c0 ^ (r & 28)] =
            *(const float4*)(K + (size_t)(rowbase + r*H_)*DK_ + c0);
    }
    if (tid < 64) {
        float g = G[rowbase + tid*H_];
        #pragma unroll
        for (int off = 1; off < 64; off <<= 1) {
            float o = __shfl_up(g, off, 64);
            if (tid >= off) g += o;
        }
        float ep = expf(g);
        epos[tid] = ep;
        eneg[tid] = expf(-g);
        bet[tid]  = Bt[rowbase + tid*H_];
        if (tid == 63) EGw[cid] = ep;
    }
    __syncthreads();

    // B: stage v*beta -> f16; k row norms -> rn, cL, cR, RK
    #pragma unroll
    for (int i = 0; i < 8; ++i) {
        int idx4 = tid + 256*i;
        int r = idx4 >> 5, c0 = (idx4 & 31) << 2;
        float bb = bet[r];
        float4 vv = *(const float4*)(V + (size_t)(rowbase + r*H_)*DV_ + c0);
        vv.x *= bb; vv.y *= bb; vv.z *= bb; vv.w *= bb;
        f4toh4(&bufh[r][c0], vv);
    }
    if (tid < 64) {
        const int xr = tid & 28;
        float s = 0.f;
        #pragma unroll
        for (int c = 0; c < 128; c += 4) { float4 x = *(float4*)&kn[tid][c ^ xr]; s += DOT4(x,x); }
        float r_ = rsqrtf(s + 1e-6f);
        rn[tid] = r_;
        RKw[cid*64 + tid] = r_*epos[63]*eneg[tid];
        cL[tid] = bet[tid]*epos[tid]*r_;
        cR[tid] = eneg[tid]*r_;
    }
    __syncthreads();

    // C: T = -strict_lower( cL(i)*cR(j) * (kraw_i . kraw_j) )
    {
        const int i0 = (tid >> 4) << 2, j0 = (tid & 15) << 2;
        const int xi = i0 & 28, xj = j0 & 28;
        float acc[4][4] = {};
        if (j0 <= i0) {
            for (int c = 0; c < 128; c += 4) {
                float4 a0 = *(float4*)&kn[i0  ][c ^ xi], a1 = *(float4*)&kn[i0+1][c ^ xi];
                float4 a2 = *(float4*)&kn[i0+2][c ^ xi], a3 = *(float4*)&kn[i0+3][c ^ xi];
                float4 b0 = *(float4*)&kn[j0  ][c ^ xj], b1 = *(float4*)&kn[j0+1][c ^ xj];
                float4 b2 = *(float4*)&kn[j0+2][c ^ xj], b3 = *(float4*)&kn[j0+3][c ^ xj];
                acc[0][0]+=DOT4(a0,b0); acc[0][1]+=DOT4(a0,b1); acc[0][2]+=DOT4(a0,b2); acc[0][3]+=DOT4(a0,b3);
                acc[1][0]+=DOT4(a1,b0); acc[1][1]+=DOT4(a1,b1); acc[1][2]+=DOT4(a1,b2); acc[1][3]+=DOT4(a1,b3);
                acc[2][0]+=DOT4(a2,b0); acc[2][1]+=DOT4(a2,b1); acc[2][2]+=DOT4(a2,b2); acc[2][3]+=DOT4(a2,b3);
                acc[3][0]+=DOT4(a3,b0); acc[3][1]+=DOT4(a3,b1); acc[3][2]+=DOT4(a3,b2); acc[3][3]+=DOT4(a3,b3);
            }
        }
        #pragma unroll
        for (int x = 0; x < 4; ++x) {
            float fi = cL[i0+x];
            #pragma unroll
            for (int y = 0; y < 4; ++y) {
                int i = i0+x, j = j0+y;
                T[i][j] = (i > j) ? (-fi*cR[j]*acc[x][y]) : 0.f;
            }
        }
    }
    __syncthreads();

    // D1: copy diagonal 16x16 blocks (original -A) into tmp
    {
        float* tf = &tmp[0][0];
        for (int t = tid; t < 1024; t += 256) {
            int d = t >> 8, i = (t >> 4) & 15, j = t & 15;
            tf[t] = T[(d<<4) + i][(d<<4) + j];
        }
    }
    __syncthreads();
    // D2: invert each diagonal block in place, one thread per (block, column)
    if (tid < 64) {
        const float* Ad = &tmp[0][0] + ((tid >> 4) << 8);
        const int j = tid & 15, R = (tid >> 4) << 4;
        for (int i = j+1; i < 16; ++i) {
            float x = Ad[(i<<4) + j];
            for (int l = j+1; l < i; ++l) x += Ad[(i<<4) + l] * T[R+l][R+j];
            T[R+i][R+j] = x;
        }
    }
    __syncthreads();
    // D3: 16 -> 32 (two pairs). X21 = (I+X22) * T21 * (I+X11)
    {
        const int p = tid >> 7, rem = tid & 127, i = rem >> 3, j0 = (rem & 7) << 1;
        const int bb2 = p << 5;
        float x0 = T[bb2+16+i][bb2+j0], x1 = T[bb2+16+i][bb2+j0+1];
        for (int l = j0+1; l < 16; ++l) {
            float a = T[bb2+16+i][bb2+l];
            x0 += a * T[bb2+l][bb2+j0];
            if (l > j0+1) x1 += a * T[bb2+l][bb2+j0+1];
        }
        tmp[(p<<4)+i][j0] = x0; tmp[(p<<4)+i][j0+1] = x1;
        __syncthreads();
        float y0 = tmp[(p<<4)+i][j0], y1 = tmp[(p<<4)+i][j0+1];
        for (int l = 0; l < i; ++l) {
            float a = T[bb2+16+i][bb2+16+l];
            y0 += a * tmp[(p<<4)+l][j0];
            y1 += a * tmp[(p<<4)+l][j0+1];
        }
        T[bb2+16+i][bb2+j0] = y0; T[bb2+16+i][bb2+j0+1] = y1;
    }
    __syncthreads();
    // D4: 32 -> 64
    {
        const int i = tid >> 3, j0 = (tid & 7) << 2;
        float x0 = T[32+i][j0], x1 = T[32+i][j0+1], x2 = T[32+i][j0+2], x3 = T[32+i][j0+3];
        for (int l = j0+1; l < 32; ++l) {
            float a = T[32+i][l];
            x0 += a * T[l][j0];
            if (l > j0+1) x1 += a * T[l][j0+1];
            if (l > j0+2) x2 += a * T[l][j0+2];
            if (l > j0+3) x3 += a * T[l][j0+3];
        }
        tmp[i][j0] = x0; tmp[i][j0+1] = x1; tmp[i][j0+2] = x2; tmp[i][j0+3] = x3;
        __syncthreads();
        float y0 = tmp[i][j0], y1 = tmp[i][j0+1], y2 = tmp[i][j0+2], y3 = tmp[i][j0+3];
        for (int l = 0; l < i; ++l) {
            float a = T[32+i][32+l];
            y0 += a * tmp[l][j0];   y1 += a * tmp[l][j0+1];
            y2 += a * tmp[l][j0+2]; y3 += a * tmp[l][j0+3];
        }
        T[32+i][j0] = y0; T[32+i][j0+1] = y1; T[32+i][j0+2] = y2; T[32+i][j0+3] = y3;
    }
    __syncthreads();

    // E: U = (I+T) @ (v*beta),  KCD = (I+T) @ (k*beta*exp(gcs))  -> bf16
    {
        unsigned short* Up = Uw + (size_t)cid*(CK_*DV_);
        for (int tt = tid; tt < 512; tt += 256) {
            const int i0 = (tt >> 5) << 2, c0 = (tt & 31) << 2;
            float4 acc[4];
            #pragma unroll
            for (int x = 0; x < 4; ++x) acc[x] = h4tof4(&bufh[i0+x][c0]);
            for (int j0 = 0; j0 <= i0; j0 += 4) {
                float4 t0 = *(float4*)&T[i0][j0],   t1 = *(float4*)&T[i0+1][j0];
                float4 t2 = *(float4*)&T[i0+2][j0], t3 = *(float4*)&T[i0+3][j0];
                float4 b0 = h4tof4(&bufh[j0][c0]),   b1 = h4tof4(&bufh[j0+1][c0]);
                float4 b2 = h4tof4(&bufh[j0+2][c0]), b3 = h4tof4(&bufh[j0+3][c0]);
                acc[0].x += t0.x*b0.x + t0.y*b1.x + t0.z*b2.x + t0.w*b3.x;
                acc[0].y += t0.x*b0.y + t0.y*b1.y + t0.z*b2.y + t0.w*b3.y;
                acc[0].z += t0.x*b0.z + t0.y*b1.z + t0.z*b2.z + t0.w*b3.z;
                acc[0].w += t0.x*b0.w + t0.y*b1.w + t0.z*b2.w + t0.w*b3.w;
                acc[1].x += t1.x*b0.x + t1.y*b1.x + t1.z*b2.x + t1.w*b3.x;
                acc[1].y += t1.x*b0.y + t1.y*b1.y + t1.z*b2.y + t1.w*b3.y;
                acc[1].z += t1.x*b0.z + t1.y*b1.z + t1.z*b2.z + t1.w*b3.z;
                acc[1].w += t1.x*b0.w + t1.y*b1.w + t1.z*b2.w + t1.w*b3.w;
                acc[2].x += t2.x*b0.x + t2.y*b1.x + t2.z*b2.x + t2.w*b3.x;
                acc[2].y += t2.x*b0.y + t2.y*b1.y + t2.z*b2.y + t2.w*b3.y;
                acc[2].z += t2.x*b0.z + t2.y*b1.z + t2.z*b2.z + t2.w*b3.z;
                acc[2].w += t2.x*b0.w + t2.y*b1.w + t2.z*b2.w + t2.w*b3.w;
                acc[3].x += t3.x*b0.x + t3.y*b1.x + t3.z*b2.x + t3.w*b3.x;
                acc[3].y += t3.x*b0.y + t3.y*b1.y + t3.z*b2.y + t3.w*b3.y;
                acc[3].z += t3.x*b0.z + t3.y*b1.z + t3.z*b2.z + t3.w*b3.z;
                acc[3].w += t3.x*b0.w + t3.y*b1.w + t3.z*b2.w + t3.w*b3.w;
            }
            #pragma unroll
            for (int x = 0; x < 4; ++x) {
                ushort4 o; o.x = f2bf(acc[x].x); o.y = f2bf(acc[x].y);
                o.z = f2bf(acc[x].z); o.w = f2bf(acc[x].w);
                *(ushort4*)(Up + (i0+x)*DV_ + c0) = o;
            }
        }
        unsigned short* Kp = KCDw + (size_t)cid*(CK_*DK_);
        for (int tt = tid; tt < 512; tt += 256) {
            const int i0 = (tt >> 5) << 2, c0 = (tt & 31) << 2;
            const int xi = i0 & 28;
            float4 acc[4];
            #pragma unroll
            for (int x = 0; x < 4; ++x) {
                float wi = cL[i0+x];
                float4 kv = *(float4*)&kn[i0+x][c0 ^ xi];
                acc[x].x = kv.x*wi; acc[x].y = kv.y*wi; acc[x].z = kv.z*wi; acc[x].w = kv.w*wi;
            }
            for (int j0 = 0; j0 <= i0; j0 += 4) {
                const int xj = j0 & 28;
                float w0 = cL[j0], w1 = cL[j0+1], w2 = cL[j0+2], w3 = cL[j0+3];
                float4 t0 = *(float4*)&T[i0][j0],   t1 = *(float4*)&T[i0+1][j0];
                float4 t2 = *(float4*)&T[i0+2][j0], t3 = *(float4*)&T[i0+3][j0];
                float4 b0 = *(float4*)&kn[j0  ][c0 ^ xj], b1 = *(float4*)&kn[j0+1][c0 ^ xj];
                float4 b2 = *(float4*)&kn[j0+2][c0 ^ xj], b3 = *(float4*)&kn[j0+3][c0 ^ xj];
                b0.x*=w0; b0.y*=w0; b0.z*=w0; b0.w*=w0;
                b1.x*=w1; b1.y*=w1; b1.z*=w1; b1.w*=w1;
                b2.x*=w2; b2.y*=w2; b2.z*=w2; b2.w*=w2;
                b3.x*=w3; b3.y*=w3; b3.z*=w3; b3.w*=w3;
                acc[0].x += t0.x*b0.x + t0.y*b1.x + t0.z*b2.x + t0.w*b3.x;
                acc[0].y += t0.x*b0.y + t0.y*b1.y + t0.z*b2.y + t0.w*b3.y;
                acc[0].z += t0.x*b0.z + t0.y*b1.z + t0.z*b2.z + t0.w*b3.z;
                acc[0].w += t0.x*b0.w + t0.y*b1.w + t0.z*b2.w + t0.w*b3.w;
                acc[1].x += t1.x*b0.x + t1.y*b1.x + t1.z*b2.x + t1.w*b3.x;
                acc[1].y += t1.x*b0.y + t1.y*b1.y + t1.z*b2.y + t1.w*b3.y;
                acc[1].z += t1.x*b0.z + t1.y*b1.z + t1.z*b2.z + t1.w*b3.z;
                acc[1].w += t1.x*b0.w + t1.y*b1.w + t1.z*b2.w + t1.w*b3.w;
                acc[2].x += t2.x*b0.x + t2.y*b1.x + t2.z*b2.x + t2.w*b3.x;
                acc[2].y += t2.x*b0.y + t2.y*b1.y + t2.z*b2.y + t2.w*b3.y;
                acc[2].z += t2.x*b0.z + t2.y*b1.z + t2.z*b2.z + t2.w*b3.z;
                acc[2].w += t2.x*b0.w + t2.y*b1.w + t2.z*b2.w + t2.w*b3.w;
                acc[3].x += t3.x*b0.x + t3.y*b1.x + t3.z*b2.x + t3.w*b3.x;
                acc[3].y += t3.x*b0.y + t3.y*b1.y + t3.z*b2.y + t3.w*b3.y;
                acc[3].z += t3.x*b0.z + t3.y*b1.z + t3.z*b2.z + t3.w*b3.z;
                acc[3].w += t3.x*b0.w + t3.y*b1.w + t3.z*b2.w + t3.w*b3.w;
            }
            #pragma unroll
            for (int x = 0; x < 4; ++x) {
                ushort4 o; o.x = f2bf(acc[x].x); o.y = f2bf(acc[x].y);
                o.z = f2bf(acc[x].z); o.w = f2bf(acc[x].w);
                *(ushort4*)(Kp + (i0+x)*DK_ + c0) = o;
            }
        }
    }
    __syncthreads();

    // F: stage raw q -> f16 (scale folded into epilogue)
    #pragma unroll
    for (int i = 0; i < 8; ++i) {
        int idx4 = tid + 256*i;
        int r = idx4 >> 5, c0 = (idx4 & 31) << 2;
        f4toh4(&bufh[r][c0], *(const float4*)(Q + (size_t)(rowbase + r*H_)*DK_ + c0));
    }
    __syncthreads();
    // G: q row norms (QSCALE folded); RQ
    if (tid < 64) {
        float s = 0.f;
        #pragma unroll
        for (int c = 0; c < 128; c += 4) { float4 x = h4tof4(&bufh[tid][c]); s += DOT4(x,x); }
        float r_ = rsqrtf(s + 1e-6f)*QSCALE;
        rn[tid] = r_;
        RQw[cid*64 + tid] = r_*epos[tid];
    }
    __syncthreads();

    // H: attn = tril(q@k^T * decay) -> bf16
    {
        unsigned short* Ap = ATTNw + (size_t)cid*(CK_*CK_);
        const int i0 = (tid >> 4) << 2, j0 = (tid & 15) << 2;
        const int xj = j0 & 28;
        float acc[4][4] = {};
        if (j0 <= i0) {
            for (int c = 0; c < 128; c += 4) {
                float4 a0 = h4tof4(&bufh[i0  ][c]), a1 = h4tof4(&bufh[i0+1][c]);
                float4 a2 = h4tof4(&bufh[i0+2][c]), a3 = h4tof4(&bufh[i0+3][c]);
                float4 b0 = *(float4*)&kn[j0  ][c ^ xj], b1 = *(float4*)&kn[j0+1][c ^ xj];
                float4 b2 = *(float4*)&kn[j0+2][c ^ xj], b3 = *(float4*)&kn[j0+3][c ^ xj];
                acc[0][0]+=DOT4(a0,b0); acc[0][1]+=DOT4(a0,b1); acc[0][2]+=DOT4(a0,b2); acc[0][3]+=DOT4(a0,b3);
                acc[1][0]+=DOT4(a1,b0); acc[1][1]+=DOT4(a1,b1); acc[1][2]+=DOT4(a1,b2); acc[1][3]+=DOT4(a1,b3);
                acc[2][0]+=DOT4(a2,b0); acc[2][1]+=DOT4(a2,b1); acc[2][2]+=DOT4(a2,b2); acc[2][3]+=DOT4(a2,b3);
                acc[3][0]+=DOT4(a3,b0); acc[3][1]+=DOT4(a3,b1); acc[3][2]+=DOT4(a3,b2); acc[3][3]+=DOT4(a3,b3);
            }
        }
        #pragma unroll
        for (int x = 0; x < 4; ++x) {
            ushort4 o;
            int i = i0+x;
            float fi = rn[i]*epos[i];
            float v0 = (j0   <= i) ? acc[x][0]*fi*cR[j0]   : 0.f;
            float v1 = (j0+1 <= i) ? acc[x][1]*fi*cR[j0+1] : 0.f;
            float v2 = (j0+2 <= i) ? acc[x][2]*fi*cR[j0+2] : 0.f;
            float v3 = (j0+3 <= i) ? acc[x][3]*fi*cR[j0+3] : 0.f;
            o.x = f2bf(v0); o.y = f2bf(v1); o.z = f2bf(v2); o.w = f2bf(v3);
            *(ushort4*)(Ap + i*CK_ + j0) = o;
        }
    }
}

// ---------------- Phase 2: state recurrence (256 blocks = bh x 8 v-slices of 16) --------
// (unchanged from round 4: wave-private state, 1 barrier/chunk, XCD-affinity remap)
#define P2_LOAD(nn) do { \
    const int cid_ = bh*NC_ + (nn); \
    const int rb_ = (b*S_ + (nn)*CK_)*H_ + h; \
    _Pragma("unroll") \
    for (int i = 0; i < 4; ++i) { \
        int idx4 = tid + 512*i; \
        int r = idx4 >> 5; \
        pk[i]  = *(const float4*)(K + (size_t)(rb_ + r*H_)*DK_ + ((idx4 & 31)*4)); \
        pc[i]  = ((const uint2*)(KCDw + (size_t)cid_*8192))[idx4]; \
        prk[i] = RKw[cid_*64 + r]; \
    } \
    pu = *(const unsigned*)(Uw + (size_t)cid_*8192 + lane*128 + v0 + 2*w); \
} while(0)

__global__ __launch_bounds__(512) void dr_phase2(
    const float* __restrict__ K,
    const unsigned short* __restrict__ Uw, const unsigned short* __restrict__ KCDw,
    const float* __restrict__ RKw, const float* __restrict__ EGw,
    unsigned short* __restrict__ STw)
{
    __shared__ __align__(16) unsigned short kch[2][64][136]; // kcd raw bf16, SWH-swizzled
    __shared__ float kd[2][64][132];   // k_norm * exp(g_last - gcs), f32
    __shared__ float stT[16][132];     // state^T slice (row v owned by wave v>>1)
    __shared__ float vnw[8][64][2];    // per-wave vn columns (write by lane, read bcast)

    const int tid = threadIdx.x;
    const int bidx = blockIdx.x;
    const int xcd  = bidx & 7;
    const int slot = bidx >> 3;            // 0..31
    const int vs   = slot >> 2;            // 0..7
    const int bh   = ((slot & 3) << 3) | xcd;   // 0..31, bh%8 == xcd
    const int h = bh & (H_-1), b = bh >> 4;
    const int v0 = vs*16;
    const int w = tid >> 6, lane = tid & 63;
    const int lva = 2*w, lvb = 2*w + 1;
    const int c2 = 2*lane;

    float2 sA = {0.f, 0.f}, sB = {0.f, 0.f};
    *(float2*)&stT[lva][c2] = sA;
    *(float2*)&stT[lvb][c2] = sB;

    float4 pk[4]; uint2 pc[4]; float prk[4]; unsigned pu;
    P2_LOAD(0);

    int cur = 0;
    for (int n = 0; n < NC_; ++n) {
        const int cid = bh*NC_ + n;
        const float u0 = bf2f((unsigned short)(pu & 0xffff));
        const float u1 = bf2f((unsigned short)(pu >> 16));

        #pragma unroll
        for (int i = 0; i < 4; ++i) {
            int idx4 = tid + 512*i;
            int r = idx4 >> 5, c0 = (idx4 & 31)*4;
            *(uint2*)&kch[cur][r][SWH(c0, r)] = pc[i];
            float4 kv = pk[i];
            kv.x *= prk[i]; kv.y *= prk[i]; kv.z *= prk[i]; kv.w *= prk[i];
            *(float4*)&kd[cur][r][c0] = kv;
        }
        if (n+1 < NC_) P2_LOAD(n+1);
        __syncthreads();

        {
            unsigned pA = (unsigned)f2bf(sA.x) | ((unsigned)f2bf(sA.y) << 16);
            unsigned pB = (unsigned)f2bf(sB.x) | ((unsigned)f2bf(sB.y) << 16);
            size_t base = ((size_t)cid*128 + v0)*128;
            *(unsigned*)(STw + base + (size_t)lva*128 + c2) = pA;
            *(unsigned*)(STw + base + (size_t)lvb*128 + c2) = pB;
        }

        float vA = u0, vB = u1;
        for (int k0 = 0; k0 < 128; k0 += 8) {
            f8 a = unp_bf16x8(*(const uint4*)&kch[cur][lane][SWH(k0, lane)]);
            float4 pa0 = *(const float4*)&stT[lva][k0], pa1 = *(const float4*)&stT[lva][k0+4];
            float4 pb0 = *(const float4*)&stT[lvb][k0], pb1 = *(const float4*)&stT[lvb][k0+4];
            vA -= DOT4(a.lo, pa0) + DOT4(a.hi, pa1);
            vB -= DOT4(a.lo, pb0) + DOT4(a.hi, pb1);
        }
        vnw[w][lane][0] = vA;
        vnw[w][lane][1] = vB;

        const float a_dec = EGw[cid];
        sA.x *= a_dec; sA.y *= a_dec; sB.x *= a_dec; sB.y *= a_dec;
        for (int r = 0; r < 64; ++r) {
            float2 vv = *(const float2*)&vnw[w][r];
            float2 kv = *(const float2*)&kd[cur][r][c2];
            sA.x += vv.x*kv.x; sA.y += vv.x*kv.y;
            sB.x += vv.y*kv.x; sB.y += vv.y*kv.y;
        }
        *(float2*)&stT[lva][c2] = sA;
        *(float2*)&stT[lvb][c2] = sB;

        cur ^= 1;
    }
}

// ---------------- Phase 3: outputs (4096 blocks = chunk x Dv-half), MFMA ----------------
// vn = u + (-kc)·S^T  and  o = qg·S^T + attn·vn  via mfma_f32_16x16x32_bf16.
// All operands bf16 in swizzled LDS; kc staged sign-flipped so C-init=u works.
// 4 waves: wave w owns rows [16w,16w+16) x 4 v-tiles of 16. LDS 70.7KB -> 2 blocks/CU.
__global__ __launch_bounds__(256) void dr_phase3(
    const float* __restrict__ Q,
    const unsigned short* __restrict__ Uw, const unsigned short* __restrict__ KCDw,
    const unsigned short* __restrict__ ATTNw, const unsigned short* __restrict__ STw,
    const float* __restrict__ RQw, float* __restrict__ Out)
{
    __shared__ __align__(16) unsigned short qbh[64][136]; // q*rq*exp(gcs) bf16 (swz)
    __shared__ __align__(16) unsigned short kch[64][136]; // -kcd bf16 (swz)
    __shared__ __align__(16) unsigned short sth[64][136]; // state^T bf16 (swz)
    __shared__ __align__(16) unsigned short ath[64][72];  // attn bf16 (swz)
    __shared__ __align__(16) unsigned short vnbh[64][72]; // vn^T bf16 (swz)

    const int tid = threadIdx.x;
    const int bidx = blockIdx.x;
    const int xcd  = bidx & 7;
    const int half = (bidx >> 3) & 1;
    const int cid  = ((bidx >> 4) << 3) | xcd;   // 0..2047
    const int n = cid & (NC_-1), bh = cid >> 6;
    const int h = bh & (H_-1), b = bh >> 4;
    const int rowbase = (b*S_ + n*CK_)*H_ + h;
    const int vbase = half*64;

    const int w = tid >> 6, l = tid & 63;
    const int R = w*16;                    // this wave's output row base
    const int lrow = l & 15;               // A-row / B-col lane index
    const int lk = (l >> 4) * 8;           // k sub-offset within 32-wide kstep
    const int lreg4 = (l >> 4) * 4;        // C/D row group

    // u loads issued first: latency hides under LDS staging below.
    float uval[4][4];                      // [vt][rg]
    {
        const unsigned short* up = Uw + (size_t)cid*8192 + (R + lreg4)*128 + vbase + lrow;
        #pragma unroll
        for (int vt = 0; vt < 4; ++vt)
            #pragma unroll
            for (int rg = 0; rg < 4; ++rg)
                uval[vt][rg] = bf2f(up[rg*128 + vt*16]);
    }

    #pragma unroll
    for (int i = 0; i < 8; ++i) {
        int idx4 = tid + 256*i;
        int r = idx4 >> 5, c0 = (idx4 & 31)*4;
        float rq = RQw[cid*64 + r];
        float4 qv = *(const float4*)(Q + (size_t)(rowbase + r*H_)*DK_ + c0);
        ushort4 qo;
        qo.x = f2bf(qv.x*rq); qo.y = f2bf(qv.y*rq);
        qo.z = f2bf(qv.z*rq); qo.w = f2bf(qv.w*rq);
        *(ushort4*)&qbh[r][SWH(c0, r)] = qo;
        uint2 kcv = ((const uint2*)(KCDw + (size_t)cid*8192))[idx4];
        kcv.x ^= 0x80008000u; kcv.y ^= 0x80008000u;     // negate kc (bf16 sign flip)
        *(uint2*)&kch[r][SWH(c0, r)] = kcv;
        uint2 stv = ((const uint2*)(STw + ((size_t)cid*128 + vbase)*128))[idx4];
        *(uint2*)&sth[r][SWH(c0, r)] = stv;
    }
    #pragma unroll
    for (int i = 0; i < 4; ++i) {
        int idx4 = tid + 256*i;
        int r = idx4 >> 4, j0 = (idx4 & 15)*4;
        uint2 av = ((const uint2*)(ATTNw + (size_t)cid*4096))[idx4];
        *(uint2*)&ath[r][SWH(j0, r)] = av;
    }
    __syncthreads();

    // vn = u + (-kc)·S^T : A = kch rows [R..R+15], B[k][v] = sth[v][k]
    f32x4 vac[4];
    #pragma unroll
    for (int vt = 0; vt < 4; ++vt) {
        vac[vt][0] = uval[vt][0]; vac[vt][1] = uval[vt][1];
        vac[vt][2] = uval[vt][2]; vac[vt][3] = uval[vt][3];
    }
    #pragma unroll
    for (int ks = 0; ks < 4; ++ks) {
        bf16x8 a = *(const bf16x8*)&kch[R + lrow][SWH(ks*32 + lk, R + lrow)];
        #pragma unroll
        for (int vt = 0; vt < 4; ++vt) {
            bf16x8 bb = *(const bf16x8*)&sth[vt*16 + lrow][SWH(ks*32 + lk, vt*16 + lrow)];
            vac[vt] = __builtin_amdgcn_mfma_f32_16x16x32_bf16(a, bb, vac[vt], 0, 0, 0);
        }
    }
    // store vn^T (bf16): lane holds vn[R+lreg4+rg][vt*16+lrow]
    #pragma unroll
    for (int vt = 0; vt < 4; ++vt) {
        ushort4 o;
        o.x = f2bf(vac[vt][0]); o.y = f2bf(vac[vt][1]);
        o.z = f2bf(vac[vt][2]); o.w = f2bf(vac[vt][3]);
        *(ushort4*)&vnbh[vt*16 + lrow][SWH(R + lreg4, vt*16 + lrow)] = o;
    }
    __syncthreads();

    // o = qg·S^T + attn·vn
    f32x4 oac[4];
    const f32x4 zero4 = {0.f, 0.f, 0.f, 0.f};
    #pragma unroll
    for (int vt = 0; vt < 4; ++vt) oac[vt] = zero4;
    #pragma unroll
    for (int ks = 0; ks < 4; ++ks) {
        bf16x8 a = *(const bf16x8*)&qbh[R + lrow][SWH(ks*32 + lk, R + lrow)];
        #pragma unroll
        for (int vt = 0; vt < 4; ++vt) {
            bf16x8 bb = *(const bf16x8*)&sth[vt*16 + lrow][SWH(ks*32 + lk, vt*16 + lrow)];
            oac[vt] = __builtin_amdgcn_mfma_f32_16x16x32_bf16(a, bb, oac[vt], 0, 0, 0);
        }
    }
    // attn part: k-dim = r' (64); rows <= R+15 needed => 1 kstep for waves 0,1; 2 for 2,3.
    const int nka = (w < 2) ? 1 : 2;
    for (int ks = 0; ks < nka; ++ks) {
        bf16x8 a = *(const bf16x8*)&ath[R + lrow][SWH(ks*32 + lk, R + lrow)];
        #pragma unroll
        for (int vt = 0; vt < 4; ++vt) {
            bf16x8 bb = *(const bf16x8*)&vnbh[vt*16 + lrow][SWH(ks*32 + lk, vt*16 + lrow)];
            oac[vt] = __builtin_amdgcn_mfma_f32_16x16x32_bf16(a, bb, oac[vt], 0, 0, 0);
        }
    }

    // epilogue: lane holds o[R+lreg4+rg][vt*16+lrow]
    #pragma unroll
    for (int vt = 0; vt < 4; ++vt)
        #pragma unroll
        for (int rg = 0; rg < 4; ++rg) {
            int row = R + lreg4 + rg;
            Out[(size_t)(rowbase + row*H_)*DV_ + vbase + vt*16 + lrow] = oac[vt][rg];
        }
}

extern "C" void kernel_launch(void* const* d_in, const int* in_sizes, int n_in,
                              void* d_out, int out_size, void* d_ws, size_t ws_size,
                              hipStream_t stream) {
    (void)in_sizes; (void)n_in; (void)out_size; (void)ws_size;
    const float* Q  = (const float*)d_in[0];
    const float* K  = (const float*)d_in[1];
    const float* V  = (const float*)d_in[2];
    const float* G  = (const float*)d_in[3];
    const float* Bt = (const float*)d_in[4];
    float* Out = (float*)d_out;

    // ws layout: U bf16 | KCD bf16 | ATTN bf16 | ST bf16 | RQ f32 | RK f32 | EG f32
    unsigned short* Uw    = (unsigned short*)d_ws;
    unsigned short* KCDw  = Uw    + (size_t)2048*64*128;
    unsigned short* ATTNw = KCDw  + (size_t)2048*64*128;
    unsigned short* STw   = ATTNw + (size_t)2048*64*64;
    float* RQw = (float*)(STw + (size_t)2048*128*128);
    float* RKw = RQw + 2048*64;
    float* EGw = RKw + 2048*64;

    dr_phase1<<<2048, 256, 0, stream>>>(Q, K, V, G, Bt, Uw, KCDw, ATTNw, RQw, RKw, EGw);
    dr_phase2<<<256, 512, 0, stream>>>(K, Uw, KCDw, RKw, EGw, STw);
    dr_phase3<<<4096, 256, 0, stream>>>(Q, Uw, KCDw, ATTNw, STw, RQw, Out);
}